// Round 11
// baseline (279.512 us; speedup 1.0000x reference)
//
#include <hip/hip_runtime.h>
#include <math.h>

// Problem constants
constexpr int N = 8, C = 128, H = 64, W = 64;
constexpr int PIX = H * W;            // 4096
constexpr int KK = 49;                // 7x7 window

// ws layout (floats)
constexpr size_t M_OFF   = 0;                        // M = W1^T W2
constexpr size_t WT3_OFF = 16384;                    // W3^T [k][o]
constexpr size_t Z_OFF   = 65536;                    // z = M^T x
constexpr size_t YSZ     = (size_t)N * C * PIX;      // 4,194,304
constexpr size_t SIM_OFF = Z_OFF + YSZ;              // sim fp32 [g=128][49][256]
constexpr size_t SIMSZ   = (size_t)N * 16 * KK * 256;// 1,605,632
constexpr size_t U_OFF   = SIM_OFF + SIMSZ;          // u = PV(x)

constexpr int SLW = 76;   // fp32 stage row width (simk2)
constexpr int SBW = 76;   // bf16 stage row width in ushorts (softpv7)
constexpr int ALR = 68;   // attn LDS r-stride (ushorts); 136B, 8B-aligned

// ---------------------------------------------------------------------------
// bf16 helpers
// ---------------------------------------------------------------------------
__device__ __forceinline__ unsigned bf16rne(float f) {
    unsigned u = __float_as_uint(f);
    u += 0x7FFFu + ((u >> 16) & 1u);
    return u >> 16;
}
__device__ __forceinline__ unsigned packbf(float a, float b) {
    return bf16rne(a) | (bf16rne(b) << 16);
}
__device__ __forceinline__ float bflo(unsigned u) { return __uint_as_float(u << 16); }
__device__ __forceinline__ float bfhi(unsigned u) { return __uint_as_float(u & 0xFFFF0000u); }

// ---------------------------------------------------------------------------
// K0: prep. Blocks 0..63: M[a][b] = sum_c W1[c][a]*W2[c][b].
//     Blocks 64..67: Wt3[c][o] = W3[o][c].
// ---------------------------------------------------------------------------
__global__ __launch_bounds__(256) void prep(const float* __restrict__ w1,
                                            const float* __restrict__ w2,
                                            const float* __restrict__ w3,
                                            float* __restrict__ Mout,
                                            float* __restrict__ wt3) {
    int bid = blockIdx.x, tid = threadIdx.x;
    if (bid < 64) {
        int a = bid * 2 + (tid >> 7);
        int b = tid & 127;
        float s = 0.f;
        for (int c = 0; c < 128; c++)
            s = fmaf(w1[c * 128 + a], w2[c * 128 + b], s);
        Mout[a * 128 + b] = s;
    } else {
        int base = (bid - 64) * 4096;
        for (int i = tid; i < 4096; i += 256) {
            int idx = base + i;
            int o = idx & 127, c = idx >> 7;
            wt3[idx] = w3[o * 128 + c];
        }
    }
}

// ---------------------------------------------------------------------------
// K1: 1x1-conv GEMM. Block tile: 128 oc x 64 px, K=128 chunked by 32.
// ---------------------------------------------------------------------------
__global__ __launch_bounds__(256) void convk(const float* __restrict__ A,
                                             const float* __restrict__ Bsrc,
                                             float* __restrict__ Yout) {
    __shared__ float la[32 * 136];
    __shared__ float lb[32 * 72];

    int bid = blockIdx.x;
    int pt  = bid & 63;
    int n   = bid >> 6;
    int p0  = pt * 64;

    const float* B = Bsrc + (size_t)n * C * PIX;
    float*       Y = Yout + (size_t)n * C * PIX;

    int tid = threadIdx.x;
    int tx  = tid & 15, ty = tid >> 4;
    int oc0 = ty * 8, px0 = tx * 4;

    float acc[8][4];
#pragma unroll
    for (int i = 0; i < 8; i++)
#pragma unroll
        for (int j = 0; j < 4; j++) acc[i][j] = 0.f;

    for (int kk = 0; kk < 128; kk += 32) {
#pragma unroll
        for (int i = 0; i < 4; i++) {
            int q   = tid + i * 256;
            int row = q >> 5;
            int c4  = (q & 31) * 4;
            *(float4*)&la[row * 136 + c4] =
                *(const float4*)&A[(kk + row) * 128 + c4];
        }
#pragma unroll
        for (int i = 0; i < 2; i++) {
            int q   = tid + i * 256;
            int row = q >> 4;
            int c4  = (q & 15) * 4;
            *(float4*)&lb[row * 72 + c4] =
                *(const float4*)&B[(size_t)(kk + row) * PIX + p0 + c4];
        }
        __syncthreads();

#pragma unroll 8
        for (int k = 0; k < 32; k++) {
            float4 a0 = *(float4*)&la[k * 136 + oc0];
            float4 a1 = *(float4*)&la[k * 136 + oc0 + 4];
            float4 b0 = *(float4*)&lb[k * 72 + px0];
            float a[8] = {a0.x, a0.y, a0.z, a0.w, a1.x, a1.y, a1.z, a1.w};
            float b[4] = {b0.x, b0.y, b0.z, b0.w};
#pragma unroll
            for (int i = 0; i < 8; i++)
#pragma unroll
                for (int j = 0; j < 4; j++)
                    acc[i][j] = fmaf(a[i], b[j], acc[i][j]);
        }
        __syncthreads();
    }

#pragma unroll
    for (int i = 0; i < 8; i++) {
        float4 v = make_float4(acc[i][0], acc[i][1], acc[i][2], acc[i][3]);
        *(float4*)&Y[(size_t)(oc0 + i) * PIX + p0 + px0] = v;
    }
}

// ---------------------------------------------------------------------------
// K2: sim[g][k][px], ONE di PER BLOCK.  (r7 version, unchanged, measured-best)
// ---------------------------------------------------------------------------
__global__ __launch_bounds__(256) void simk2(const float* __restrict__ z,
                                             const float* __restrict__ x,
                                             float* __restrict__ sim) {
    __shared__ __align__(16) float st[5376];

    int bid = blockIdx.x;
    int di  = bid >> 7;
    int g   = bid & 127;
    int n   = g >> 4;
    int hq  = g & 15;
    int h0  = hq * 4;

    int tid  = threadIdx.x;
    int wid  = tid >> 6;
    int lane = tid & 63;
    int r = lane >> 4, w4 = lane & 15, wpx = w4 * 4;

    const float* zb = z + (size_t)n * C * PIX;
    const float* xb = x + (size_t)n * C * PIX;
    float* simb = sim + ((size_t)g * KK) * 256;

    for (int idx = tid; idx < 16 * 4 * 8; idx += 256) {
        int col8 = idx & 7;
        int row  = (idx >> 3) & 3;
        int c    = idx >> 5;
        int col  = (col8 < 4) ? col8 : 64 + col8;
        st[(c * 4 + row) * SLW + col] = 0.f;
    }
    __syncthreads();

    float acc[7][4];
#pragma unroll
    for (int dj = 0; dj < 7; dj++)
#pragma unroll
        for (int j = 0; j < 4; j++) acc[dj][j] = 0.f;

    for (int ch = 0; ch < C; ch += 16) {
#pragma unroll
        for (int i = 0; i < 4; i++) {
            int q  = tid + i * 256;
            int qw = q & 15, qc = (q >> 4) & 15, qr = q >> 8;
            int hh = h0 + di - 3 + qr;
            float4 v = make_float4(0.f, 0.f, 0.f, 0.f);
            if ((unsigned)hh < 64u)
                v = *(const float4*)&xb[(size_t)(ch + qc) * PIX + hh * 64 + qw * 4];
            *(float4*)&st[(qc * 4 + qr) * SLW + 4 + qw * 4] = v;
        }
        __syncthreads();

#pragma unroll
        for (int c = 0; c < 4; c++) {
            int cl = wid * 4 + c;
            float4 z4 = *(const float4*)&zb[(size_t)(ch + cl) * PIX + (h0 + r) * 64 + wpx];
            const float* rp = &st[(cl * 4 + r) * SLW + wpx];
            float rw[12];
            *(float4*)&rw[0] = *(const float4*)&rp[0];
            *(float4*)&rw[4] = *(const float4*)&rp[4];
            *(float4*)&rw[8] = *(const float4*)&rp[8];
            const float* zp = (const float*)&z4;
#pragma unroll
            for (int dj = 0; dj < 7; dj++)
#pragma unroll
                for (int j = 0; j < 4; j++)
                    acc[dj][j] = fmaf(zp[j], rw[j + dj + 1], acc[dj][j]);
        }
        __syncthreads();
    }

    if (wid > 0) {
#pragma unroll
        for (int dj = 0; dj < 7; dj++) {
            float4 v = make_float4(acc[dj][0], acc[dj][1], acc[dj][2], acc[dj][3]);
            *(float4*)&st[((wid - 1) * 7 + dj) * 256 + lane * 4] = v;
        }
    }
    __syncthreads();
    if (wid == 0) {
#pragma unroll
        for (int s = 0; s < 3; s++)
#pragma unroll
            for (int dj = 0; dj < 7; dj++) {
                float4 v = *(const float4*)&st[(s * 7 + dj) * 256 + lane * 4];
                acc[dj][0] += v.x; acc[dj][1] += v.y;
                acc[dj][2] += v.z; acc[dj][3] += v.w;
            }
#pragma unroll
        for (int dj = 0; dj < 7; dj++) {
            int k = di * 7 + dj;
            float4 v = make_float4(acc[dj][0], acc[dj][1], acc[dj][2], acc[dj][3]);
            *(float4*)&simb[(size_t)k * 256 + r * 64 + wpx] = v;
        }
    }
}

// ---------------------------------------------------------------------------
// K3: integrated softmax (deferred normalization) + PV.
// Grid 512: bid = cqb*128 + g.  512 thr = 8 waves.  Lane r = lane>>4 (4 rows),
// w4 = lane&15 (4 px).  Wave cw = wid*2 channels; 2 chunks of 16 ch.
// LDS: bf16 window stage (24.3 KB) + bf16 unnorm-attn (26.7 KB) + sinv (1 KB)
//      + mred/sred aliased over stage  -> 52 KB -> 3 blocks/CU.
// __launch_bounds__(512,6): cap VGPR at 85 so 6 waves/SIMD are resident.
// ---------------------------------------------------------------------------
__global__ __launch_bounds__(512, 6) void softpv7(const float* __restrict__ sim,
                                                  const float* __restrict__ x,
                                                  float* __restrict__ u) {
    __shared__ __align__(16) unsigned short stb[16 * 10 * SBW]; // 24,320 B
    __shared__ __align__(16) unsigned short al[KK * 4 * ALR];   // 26,656 B
    __shared__ float sinv[256];                                 // 1,024 B
    float* mred = (float*)stb;          // [2][256] alias (dead before staging)
    float* sred = (float*)stb + 512;    // [2][256] alias

    int bid = blockIdx.x;
    int cqb = bid >> 7;
    int g   = bid & 127;
    int n   = g >> 4;
    int hq  = g & 15;
    int h0  = hq * 4;

    int tid  = threadIdx.x;
    int wid  = tid >> 6;
    int lane = tid & 63;
    int r = lane >> 4, w4 = lane & 15, wpx = w4 * 4;

    const float* simb = sim + (size_t)g * KK * 256;
    const float* xb   = x + (size_t)n * C * PIX;
    float* ub = u + (size_t)n * C * PIX;

    // ---- Phase 1: softmax, k-split over thread halves; unnormalized e ----
    {
        int ks = tid >> 8;            // 0/1
        int px = tid & 255;
        int k0 = ks ? 25 : 0;
        int nk = ks ? 24 : 25;
        float m = -1e30f;
        for (int i = 0; i < nk; i++)
            m = fmaxf(m, simb[(size_t)(k0 + i) * 256 + px]);
        mred[ks * 256 + px] = m;
        __syncthreads();
        m = fmaxf(mred[px], mred[256 + px]);
        float s = 0.f;
        int pr = px >> 6, pw = px & 63;
        for (int i = 0; i < nk; i++) {
            float e = __expf(simb[(size_t)(k0 + i) * 256 + px] - m);
            s += e;
            al[(k0 + i) * (4 * ALR) + pr * ALR + pw] = (unsigned short)bf16rne(e);
        }
        sred[ks * 256 + px] = s;      // distinct region from mred reads
        __syncthreads();
        if (ks == 0) sinv[px] = 1.f / (sred[px] + sred[256 + px]);
    }
    __syncthreads();   // sinv ready; stb (mred/sred alias) reusable

    // ---- zero halo cols (0..3, 68..75) once ----
    for (int idx = tid; idx < 16 * 10 * 12; idx += 512) {
        int i12 = idx % 12;
        int rowc = idx / 12;          // c*10+row
        int col = (i12 < 4) ? i12 : 64 + i12;
        stb[rowc * SBW + col] = 0;
    }
    // (halo zero completes before first stage write via the barrier below)

    for (int ch2 = 0; ch2 < 2; ch2++) {
        int c0 = cqb * 32 + ch2 * 16;
        // ---- stage 16 ch x 10 rows, bf16-packed ----
        for (int i = 0; i < 5; i++) {
            int q   = tid + i * 512;            // 0..2559 over f4 units
            int c   = q / 160;
            int rem = q - c * 160;
            int row = rem >> 4;
            int w16 = rem & 15;
            int hh  = h0 - 3 + row;
            float4 v = make_float4(0.f, 0.f, 0.f, 0.f);
            if ((unsigned)hh < 64u)
                v = *(const float4*)&xb[(size_t)(c0 + c) * PIX + hh * 64 + w16 * 4];
            uint2 p;
            p.x = packbf(v.x, v.y);
            p.y = packbf(v.z, v.w);
            *(uint2*)&stb[(c * 10 + row) * SBW + 4 + w16 * 4] = p;
        }
        __syncthreads();

        // ---- PV ----
        int cw = wid * 2;
        float u4[2][4];
#pragma unroll
        for (int cl = 0; cl < 2; cl++)
#pragma unroll
            for (int j = 0; j < 4; j++) u4[cl][j] = 0.f;

        for (int di = 0; di < 7; di++) {
            float a[7][4];
#pragma unroll
            for (int dj = 0; dj < 7; dj++) {
                uint2 p = *(const uint2*)&al[(di * 7 + dj) * (4 * ALR) + r * ALR + wpx];
                a[dj][0] = bflo(p.x);
                a[dj][1] = bfhi(p.x);
                a[dj][2] = bflo(p.y);
                a[dj][3] = bfhi(p.y);
            }
#pragma unroll
            for (int cl = 0; cl < 2; cl++) {
                const unsigned short* rp = &stb[((cw + cl) * 10 + r + di) * SBW + wpx];
                uint2 q0 = *(const uint2*)&rp[0];
                uint2 q1 = *(const uint2*)&rp[4];
                uint2 q2 = *(const uint2*)&rp[8];
                float rw[12];
                rw[0] = bflo(q0.x); rw[1] = bfhi(q0.x);
                rw[2] = bflo(q0.y); rw[3] = bfhi(q0.y);
                rw[4] = bflo(q1.x); rw[5] = bfhi(q1.x);
                rw[6] = bflo(q1.y); rw[7] = bfhi(q1.y);
                rw[8] = bflo(q2.x); rw[9] = bfhi(q2.x);
                rw[10] = bflo(q2.y); rw[11] = bfhi(q2.y);
#pragma unroll
                for (int dj = 0; dj < 7; dj++)
#pragma unroll
                    for (int j = 0; j < 4; j++)
                        u4[cl][j] = fmaf(a[dj][j], rw[j + dj + 1], u4[cl][j]);
            }
        }

        // ---- epilogue: apply deferred 1/S, write ----
        float4 s4 = *(const float4*)&sinv[r * 64 + wpx];
        const float* sp = (const float*)&s4;
#pragma unroll
        for (int cl = 0; cl < 2; cl++) {
            int c = c0 + cw + cl;
            float4 v = make_float4(u4[cl][0] * sp[0], u4[cl][1] * sp[1],
                                   u4[cl][2] * sp[2], u4[cl][3] * sp[3]);
            *(float4*)&ub[(size_t)c * PIX + (h0 + r) * 64 + wpx] = v;
        }
        __syncthreads();
    }
}

// ---------------------------------------------------------------------------
extern "C" void kernel_launch(void* const* d_in, const int* in_sizes, int n_in,
                              void* d_out, int out_size, void* d_ws, size_t ws_size,
                              hipStream_t stream) {
    const float* x  = (const float*)d_in[0];
    const float* w1 = (const float*)d_in[1];
    const float* w2 = (const float*)d_in[2];
    const float* w3 = (const float*)d_in[3];
    float* wsf = (float*)d_ws;

    prep<<<68, 256, 0, stream>>>(w1, w2, w3, wsf + M_OFF, wsf + WT3_OFF);
    convk<<<512, 256, 0, stream>>>(wsf + M_OFF, x, wsf + Z_OFF);               // z = M^T x
    simk2<<<896, 256, 0, stream>>>(wsf + Z_OFF, x, wsf + SIM_OFF);             // sim
    softpv7<<<512, 512, 0, stream>>>(wsf + SIM_OFF, x, wsf + U_OFF);           // softmax+PV
    convk<<<512, 256, 0, stream>>>(wsf + WT3_OFF, wsf + U_OFF, (float*)d_out); // out = W3 u
}

// Round 12
// 121.151 us; speedup vs baseline: 2.3071x; 2.3071x over previous
//
#include <hip/hip_runtime.h>
#include <math.h>

// Problem constants
constexpr int N = 8, C = 128, H = 64, W = 64;
constexpr int PIX = H * W;            // 4096
constexpr int KK = 49;                // 7x7 window

// ws layout (floats)
constexpr size_t M_OFF   = 0;                        // M = W1^T W2
constexpr size_t WT3_OFF = 16384;                    // W3^T [k][o]
constexpr size_t Z_OFF   = 65536;                    // z = M^T x
constexpr size_t YSZ     = (size_t)N * C * PIX;      // 4,194,304
constexpr size_t SIM_OFF = Z_OFF + YSZ;              // sim fp32 [g=128][49][256]
constexpr size_t SIMSZ   = (size_t)N * 16 * KK * 256;// 1,605,632
constexpr size_t U_OFF   = SIM_OFF + SIMSZ;          // u = PV(x)

constexpr int SLW = 76;   // padded stage row width; image col v -> col 4+v

__device__ __forceinline__ unsigned bf16rne(float f) {
    unsigned u = __float_as_uint(f);
    u += 0x7FFFu + ((u >> 16) & 1u);
    return u >> 16;
}

// ---------------------------------------------------------------------------
// K0: prep. Blocks 0..63: M[a][b] = sum_c W1[c][a]*W2[c][b].
//     Blocks 64..67: Wt3[c][o] = W3[o][c].
// ---------------------------------------------------------------------------
__global__ __launch_bounds__(256) void prep(const float* __restrict__ w1,
                                            const float* __restrict__ w2,
                                            const float* __restrict__ w3,
                                            float* __restrict__ Mout,
                                            float* __restrict__ wt3) {
    int bid = blockIdx.x, tid = threadIdx.x;
    if (bid < 64) {
        int a = bid * 2 + (tid >> 7);
        int b = tid & 127;
        float s = 0.f;
        for (int c = 0; c < 128; c++)
            s = fmaf(w1[c * 128 + a], w2[c * 128 + b], s);
        Mout[a * 128 + b] = s;
    } else {
        int base = (bid - 64) * 4096;
        for (int i = tid; i < 4096; i += 256) {
            int idx = base + i;
            int o = idx & 127, c = idx >> 7;
            wt3[idx] = w3[o * 128 + c];
        }
    }
}

// ---------------------------------------------------------------------------
// K1: 1x1-conv GEMM. Block tile: 128 oc x 64 px, K=128 chunked by 32.
// (measured-good; unchanged since r4)
// ---------------------------------------------------------------------------
__global__ __launch_bounds__(256) void convk(const float* __restrict__ A,
                                             const float* __restrict__ Bsrc,
                                             float* __restrict__ Yout) {
    __shared__ float la[32 * 136];
    __shared__ float lb[32 * 72];

    int bid = blockIdx.x;
    int pt  = bid & 63;
    int n   = bid >> 6;
    int p0  = pt * 64;

    const float* B = Bsrc + (size_t)n * C * PIX;
    float*       Y = Yout + (size_t)n * C * PIX;

    int tid = threadIdx.x;
    int tx  = tid & 15, ty = tid >> 4;
    int oc0 = ty * 8, px0 = tx * 4;

    float acc[8][4];
#pragma unroll
    for (int i = 0; i < 8; i++)
#pragma unroll
        for (int j = 0; j < 4; j++) acc[i][j] = 0.f;

    for (int kk = 0; kk < 128; kk += 32) {
#pragma unroll
        for (int i = 0; i < 4; i++) {
            int q   = tid + i * 256;
            int row = q >> 5;
            int c4  = (q & 31) * 4;
            *(float4*)&la[row * 136 + c4] =
                *(const float4*)&A[(kk + row) * 128 + c4];
        }
#pragma unroll
        for (int i = 0; i < 2; i++) {
            int q   = tid + i * 256;
            int row = q >> 4;
            int c4  = (q & 15) * 4;
            *(float4*)&lb[row * 72 + c4] =
                *(const float4*)&B[(size_t)(kk + row) * PIX + p0 + c4];
        }
        __syncthreads();

#pragma unroll 8
        for (int k = 0; k < 32; k++) {
            float4 a0 = *(float4*)&la[k * 136 + oc0];
            float4 a1 = *(float4*)&la[k * 136 + oc0 + 4];
            float4 b0 = *(float4*)&lb[k * 72 + px0];
            float a[8] = {a0.x, a0.y, a0.z, a0.w, a1.x, a1.y, a1.z, a1.w};
            float b[4] = {b0.x, b0.y, b0.z, b0.w};
#pragma unroll
            for (int i = 0; i < 8; i++)
#pragma unroll
                for (int j = 0; j < 4; j++)
                    acc[i][j] = fmaf(a[i], b[j], acc[i][j]);
        }
        __syncthreads();
    }

#pragma unroll
    for (int i = 0; i < 8; i++) {
        float4 v = make_float4(acc[i][0], acc[i][1], acc[i][2], acc[i][3]);
        *(float4*)&Y[(size_t)(oc0 + i) * PIX + p0 + px0] = v;
    }
}

// ---------------------------------------------------------------------------
// K2: sim[g][k][px], ONE di PER BLOCK.  r7 structure; single change: chunk 32
// channels (4 chunks, 8 barriers) instead of 16 (8 chunks, 16 barriers).
// Stage layout c-major: st[(c*4 + row)*SLW + col]; r-stride 76 ≡ 12 banks.
// ---------------------------------------------------------------------------
__global__ __launch_bounds__(256) void simk3(const float* __restrict__ z,
                                             const float* __restrict__ x,
                                             float* __restrict__ sim) {
    __shared__ __align__(16) float st[32 * 4 * SLW];   // 9728 f (>= red 5376)

    int bid = blockIdx.x;
    int di  = bid >> 7;          // 0..6
    int g   = bid & 127;
    int n   = g >> 4;
    int hq  = g & 15;
    int h0  = hq * 4;

    int tid  = threadIdx.x;
    int wid  = tid >> 6;
    int lane = tid & 63;
    int r = lane >> 4, w4 = lane & 15, wpx = w4 * 4;

    const float* zb = z + (size_t)n * C * PIX;
    const float* xb = x + (size_t)n * C * PIX;
    float* simb = sim + ((size_t)g * KK) * 256;

    // zero halo columns (32 c x 4 rows x 8 halo cols)
    for (int idx = tid; idx < 32 * 4 * 8; idx += 256) {
        int col8 = idx & 7;
        int row  = (idx >> 3) & 3;
        int c    = idx >> 5;
        int col  = (col8 < 4) ? col8 : 64 + col8;
        st[(c * 4 + row) * SLW + col] = 0.f;
    }
    __syncthreads();

    float acc[7][4];
#pragma unroll
    for (int dj = 0; dj < 7; dj++)
#pragma unroll
        for (int j = 0; j < 4; j++) acc[dj][j] = 0.f;

    for (int ch = 0; ch < C; ch += 32) {
        // stage 32 c x 4 rows x 16 f4 = 2048 f4, 8 per thread
#pragma unroll
        for (int i = 0; i < 8; i++) {
            int q   = tid + i * 256;
            int w16 = q & 15;
            int qr  = (q >> 4) & 3;
            int qc  = q >> 6;            // 0..31
            int hh  = h0 + di - 3 + qr;
            float4 v = make_float4(0.f, 0.f, 0.f, 0.f);
            if ((unsigned)hh < 64u)
                v = *(const float4*)&xb[(size_t)(ch + qc) * PIX + hh * 64 + w16 * 4];
            *(float4*)&st[(qc * 4 + qr) * SLW + 4 + w16 * 4] = v;
        }
        __syncthreads();

#pragma unroll
        for (int c = 0; c < 8; c++) {
            int cl = wid * 8 + c;        // block-local channel 0..31
            float4 z4 = *(const float4*)&zb[(size_t)(ch + cl) * PIX + (h0 + r) * 64 + wpx];
            const float* rp = &st[(cl * 4 + r) * SLW + wpx];
            float rw[12];
            *(float4*)&rw[0] = *(const float4*)&rp[0];
            *(float4*)&rw[4] = *(const float4*)&rp[4];
            *(float4*)&rw[8] = *(const float4*)&rp[8];
            const float* zp = (const float*)&z4;
#pragma unroll
            for (int dj = 0; dj < 7; dj++)
#pragma unroll
                for (int j = 0; j < 4; j++)
                    acc[dj][j] = fmaf(zp[j], rw[j + dj + 1], acc[dj][j]);
        }
        __syncthreads();
    }

    // cross-wave reduce (st aliased; indices < 5376 < 9728)
    if (wid > 0) {
#pragma unroll
        for (int dj = 0; dj < 7; dj++) {
            float4 v = make_float4(acc[dj][0], acc[dj][1], acc[dj][2], acc[dj][3]);
            *(float4*)&st[((wid - 1) * 7 + dj) * 256 + lane * 4] = v;
        }
    }
    __syncthreads();
    if (wid == 0) {
#pragma unroll
        for (int s = 0; s < 3; s++)
#pragma unroll
            for (int dj = 0; dj < 7; dj++) {
                float4 v = *(const float4*)&st[(s * 7 + dj) * 256 + lane * 4];
                acc[dj][0] += v.x; acc[dj][1] += v.y;
                acc[dj][2] += v.z; acc[dj][3] += v.w;
            }
#pragma unroll
        for (int dj = 0; dj < 7; dj++) {
            int k = di * 7 + dj;
            float4 v = make_float4(acc[dj][0], acc[dj][1], acc[dj][2], acc[dj][3]);
            *(float4*)&simb[(size_t)k * 256 + r * 64 + wpx] = v;
        }
    }
}

// ---------------------------------------------------------------------------
// K3: softmax(sim) -> attn bf16 LDS -> u[c](p) = sum_k attn_k(p) x_c(p+dk).
// r7 structure (grid 512 = cqb*128+g, 512 thr); single change: softmax phase
// k-split across BOTH thread halves (was tid<256 with half the block idle).
// Stage c-major st[(c*10+row)*SLW+col]; attn al[k*256 + r*64 + w] bf16.
// ---------------------------------------------------------------------------
__global__ __launch_bounds__(512) void softpv4(const float* __restrict__ sim,
                                               const float* __restrict__ x,
                                               float* __restrict__ u) {
    __shared__ __align__(16) float st[16 * 10 * SLW];      // 48.6 KB
    __shared__ __align__(16) unsigned short al[KK * 256];  // 25.1 KB
    float* mred = st;          // [2][256] alias (stage dead during softmax)
    float* sred = st + 512;    // [2][256]

    int bid = blockIdx.x;
    int cqb = bid >> 7;          // 0..3 c-quarter
    int g   = bid & 127;
    int n   = g >> 4;
    int hq  = g & 15;
    int h0  = hq * 4;

    int tid  = threadIdx.x;
    int wid  = tid >> 6;
    int lane = tid & 63;
    int r = lane >> 4, w4 = lane & 15, wpx = w4 * 4;

    const float* simb = sim + (size_t)g * KK * 256;
    const float* xb   = x + (size_t)n * C * PIX;
    float* ub = u + (size_t)n * C * PIX;

    // ---- Phase 1: softmax, k-split over thread halves ----
    {
        int ks = tid >> 8;            // 0/1
        int px = tid & 255;
        int k0 = ks ? 25 : 0;
        int nk = ks ? 24 : 25;
        float sv[25];
        float m = -1e30f;
        for (int i = 0; i < nk; i++) {
            sv[i] = simb[(size_t)(k0 + i) * 256 + px];
            m = fmaxf(m, sv[i]);
        }
        mred[ks * 256 + px] = m;
        __syncthreads();
        m = fmaxf(mred[px], mred[256 + px]);
        float s = 0.f;
        for (int i = 0; i < nk; i++) {
            float e = __expf(sv[i] - m);
            sv[i] = e; s += e;
        }
        sred[ks * 256 + px] = s;
        __syncthreads();
        float inv = 1.f / (sred[px] + sred[256 + px]);
        for (int i = 0; i < nk; i++)
            al[(k0 + i) * 256 + px] = (unsigned short)bf16rne(sv[i] * inv);
    }
    __syncthreads();   // all sred reads done; st reusable for staging

    // ---- zero halo cols once ----
    for (int idx = tid; idx < 16 * 10 * 8; idx += 512) {
        int col8 = idx & 7;
        int row  = (idx >> 3) % 10;
        int c    = (idx >> 3) / 10;
        int col  = (col8 < 4) ? col8 : 64 + col8;
        st[(c * 10 + row) * SLW + col] = 0.f;
    }

    for (int ch2 = 0; ch2 < 2; ch2++) {
        int c0 = cqb * 32 + ch2 * 16;
        // stage 16 c x 10 rows (c-major)
#pragma unroll
        for (int i = 0; i < 5; i++) {
            int q  = tid + i * 512;
            int qw = q & 15, qc = (q >> 4) & 15, qr = q >> 8;
            int hh = h0 - 3 + qr;
            float4 v = make_float4(0.f, 0.f, 0.f, 0.f);
            if ((unsigned)hh < 64u)
                v = *(const float4*)&xb[(size_t)(c0 + qc) * PIX + hh * 64 + qw * 4];
            *(float4*)&st[(qc * 10 + qr) * SLW + 4 + qw * 4] = v;
        }
        __syncthreads();

        int cw = wid * 2;
        float u4[2][4];
#pragma unroll
        for (int cl = 0; cl < 2; cl++)
#pragma unroll
            for (int j = 0; j < 4; j++) u4[cl][j] = 0.f;

        for (int di = 0; di < 7; di++) {
            float a[7][4];
#pragma unroll
            for (int dj = 0; dj < 7; dj++) {
                uint2 p = *(const uint2*)&al[(di * 7 + dj) * 256 + r * 64 + wpx];
                a[dj][0] = __uint_as_float((p.x & 0xFFFFu) << 16);
                a[dj][1] = __uint_as_float(p.x & 0xFFFF0000u);
                a[dj][2] = __uint_as_float((p.y & 0xFFFFu) << 16);
                a[dj][3] = __uint_as_float(p.y & 0xFFFF0000u);
            }
#pragma unroll
            for (int cl = 0; cl < 2; cl++) {
                const float* rp = &st[((cw + cl) * 10 + r + di) * SLW + wpx];
                float rw[12];
                *(float4*)&rw[0] = *(const float4*)&rp[0];
                *(float4*)&rw[4] = *(const float4*)&rp[4];
                *(float4*)&rw[8] = *(const float4*)&rp[8];
#pragma unroll
                for (int dj = 0; dj < 7; dj++)
#pragma unroll
                    for (int j = 0; j < 4; j++)
                        u4[cl][j] = fmaf(a[dj][j], rw[j + dj + 1], u4[cl][j]);
            }
        }

#pragma unroll
        for (int cl = 0; cl < 2; cl++) {
            int c = c0 + cw + cl;
            float4 v = make_float4(u4[cl][0], u4[cl][1], u4[cl][2], u4[cl][3]);
            *(float4*)&ub[(size_t)c * PIX + (h0 + r) * 64 + wpx] = v;
        }
        __syncthreads();
    }
}

// ---------------------------------------------------------------------------
extern "C" void kernel_launch(void* const* d_in, const int* in_sizes, int n_in,
                              void* d_out, int out_size, void* d_ws, size_t ws_size,
                              hipStream_t stream) {
    const float* x  = (const float*)d_in[0];
    const float* w1 = (const float*)d_in[1];
    const float* w2 = (const float*)d_in[2];
    const float* w3 = (const float*)d_in[3];
    float* wsf = (float*)d_ws;

    prep<<<68, 256, 0, stream>>>(w1, w2, w3, wsf + M_OFF, wsf + WT3_OFF);
    convk<<<512, 256, 0, stream>>>(wsf + M_OFF, x, wsf + Z_OFF);               // z = M^T x
    simk3<<<896, 256, 0, stream>>>(wsf + Z_OFF, x, wsf + SIM_OFF);             // sim
    softpv4<<<512, 512, 0, stream>>>(wsf + SIM_OFF, x, wsf + U_OFF);           // softmax+PV
    convk<<<512, 256, 0, stream>>>(wsf + WT3_OFF, wsf + U_OFF, (float*)d_out); // out = W3 u
}

// Round 13
// 114.331 us; speedup vs baseline: 2.4448x; 1.0597x over previous
//
#include <hip/hip_runtime.h>
#include <math.h>

// Problem constants
constexpr int N = 8, C = 128, H = 64, W = 64;
constexpr int PIX = H * W;            // 4096
constexpr int KK = 49;                // 7x7 window

// ws layout (floats)
constexpr size_t M_OFF   = 0;                        // M = W1^T W2
constexpr size_t WT3_OFF = 16384;                    // W3^T [k][o]
constexpr size_t Z_OFF   = 65536;                    // z = M^T x
constexpr size_t YSZ     = (size_t)N * C * PIX;      // 4,194,304
constexpr size_t SIM_OFF = Z_OFF + YSZ;              // sim fp32 [g=128][49][256]
constexpr size_t SIMSZ   = (size_t)N * 16 * KK * 256;// 1,605,632
constexpr size_t U_OFF   = SIM_OFF + SIMSZ;          // u = PV(x)

constexpr int SLW = 76;   // fp32 stage row width (simk2)
constexpr int SBW = 76;   // bf16 stage row width in ushorts (softpv8)

__device__ __forceinline__ unsigned bf16rne(float f) {
    unsigned u = __float_as_uint(f);
    u += 0x7FFFu + ((u >> 16) & 1u);
    return u >> 16;
}
__device__ __forceinline__ unsigned packbf(float a, float b) {
    return bf16rne(a) | (bf16rne(b) << 16);
}
__device__ __forceinline__ float bflo(unsigned u) { return __uint_as_float(u << 16); }
__device__ __forceinline__ float bfhi(unsigned u) { return __uint_as_float(u & 0xFFFF0000u); }

// ---------------------------------------------------------------------------
// K0: prep. Blocks 0..63: M[a][b] = sum_c W1[c][a]*W2[c][b].
//     Blocks 64..67: Wt3[c][o] = W3[o][c].
// ---------------------------------------------------------------------------
__global__ __launch_bounds__(256) void prep(const float* __restrict__ w1,
                                            const float* __restrict__ w2,
                                            const float* __restrict__ w3,
                                            float* __restrict__ Mout,
                                            float* __restrict__ wt3) {
    int bid = blockIdx.x, tid = threadIdx.x;
    if (bid < 64) {
        int a = bid * 2 + (tid >> 7);
        int b = tid & 127;
        float s = 0.f;
        for (int c = 0; c < 128; c++)
            s = fmaf(w1[c * 128 + a], w2[c * 128 + b], s);
        Mout[a * 128 + b] = s;
    } else {
        int base = (bid - 64) * 4096;
        for (int i = tid; i < 4096; i += 256) {
            int idx = base + i;
            int o = idx & 127, c = idx >> 7;
            wt3[idx] = w3[o * 128 + c];
        }
    }
}

// ---------------------------------------------------------------------------
// K1: 1x1-conv GEMM. Block tile: 128 oc x 64 px, K=128 chunked by 32.
// (measured-good; unchanged since r4)
// ---------------------------------------------------------------------------
__global__ __launch_bounds__(256) void convk(const float* __restrict__ A,
                                             const float* __restrict__ Bsrc,
                                             float* __restrict__ Yout) {
    __shared__ float la[32 * 136];
    __shared__ float lb[32 * 72];

    int bid = blockIdx.x;
    int pt  = bid & 63;
    int n   = bid >> 6;
    int p0  = pt * 64;

    const float* B = Bsrc + (size_t)n * C * PIX;
    float*       Y = Yout + (size_t)n * C * PIX;

    int tid = threadIdx.x;
    int tx  = tid & 15, ty = tid >> 4;
    int oc0 = ty * 8, px0 = tx * 4;

    float acc[8][4];
#pragma unroll
    for (int i = 0; i < 8; i++)
#pragma unroll
        for (int j = 0; j < 4; j++) acc[i][j] = 0.f;

    for (int kk = 0; kk < 128; kk += 32) {
#pragma unroll
        for (int i = 0; i < 4; i++) {
            int q   = tid + i * 256;
            int row = q >> 5;
            int c4  = (q & 31) * 4;
            *(float4*)&la[row * 136 + c4] =
                *(const float4*)&A[(kk + row) * 128 + c4];
        }
#pragma unroll
        for (int i = 0; i < 2; i++) {
            int q   = tid + i * 256;
            int row = q >> 4;
            int c4  = (q & 15) * 4;
            *(float4*)&lb[row * 72 + c4] =
                *(const float4*)&B[(size_t)(kk + row) * PIX + p0 + c4];
        }
        __syncthreads();

#pragma unroll 8
        for (int k = 0; k < 32; k++) {
            float4 a0 = *(float4*)&la[k * 136 + oc0];
            float4 a1 = *(float4*)&la[k * 136 + oc0 + 4];
            float4 b0 = *(float4*)&lb[k * 72 + px0];
            float a[8] = {a0.x, a0.y, a0.z, a0.w, a1.x, a1.y, a1.z, a1.w};
            float b[4] = {b0.x, b0.y, b0.z, b0.w};
#pragma unroll
            for (int i = 0; i < 8; i++)
#pragma unroll
                for (int j = 0; j < 4; j++)
                    acc[i][j] = fmaf(a[i], b[j], acc[i][j]);
        }
        __syncthreads();
    }

#pragma unroll
    for (int i = 0; i < 8; i++) {
        float4 v = make_float4(acc[i][0], acc[i][1], acc[i][2], acc[i][3]);
        *(float4*)&Y[(size_t)(oc0 + i) * PIX + p0 + px0] = v;
    }
}

// ---------------------------------------------------------------------------
// K2: sim[g][k][px], ONE di PER BLOCK.  (r7 simk2, 16c chunks — measured best)
// ---------------------------------------------------------------------------
__global__ __launch_bounds__(256) void simk2(const float* __restrict__ z,
                                             const float* __restrict__ x,
                                             float* __restrict__ sim) {
    __shared__ __align__(16) float st[5376];

    int bid = blockIdx.x;
    int di  = bid >> 7;
    int g   = bid & 127;
    int n   = g >> 4;
    int hq  = g & 15;
    int h0  = hq * 4;

    int tid  = threadIdx.x;
    int wid  = tid >> 6;
    int lane = tid & 63;
    int r = lane >> 4, w4 = lane & 15, wpx = w4 * 4;

    const float* zb = z + (size_t)n * C * PIX;
    const float* xb = x + (size_t)n * C * PIX;
    float* simb = sim + ((size_t)g * KK) * 256;

    for (int idx = tid; idx < 16 * 4 * 8; idx += 256) {
        int col8 = idx & 7;
        int row  = (idx >> 3) & 3;
        int c    = idx >> 5;
        int col  = (col8 < 4) ? col8 : 64 + col8;
        st[(c * 4 + row) * SLW + col] = 0.f;
    }
    __syncthreads();

    float acc[7][4];
#pragma unroll
    for (int dj = 0; dj < 7; dj++)
#pragma unroll
        for (int j = 0; j < 4; j++) acc[dj][j] = 0.f;

    for (int ch = 0; ch < C; ch += 16) {
#pragma unroll
        for (int i = 0; i < 4; i++) {
            int q  = tid + i * 256;
            int qw = q & 15, qc = (q >> 4) & 15, qr = q >> 8;
            int hh = h0 + di - 3 + qr;
            float4 v = make_float4(0.f, 0.f, 0.f, 0.f);
            if ((unsigned)hh < 64u)
                v = *(const float4*)&xb[(size_t)(ch + qc) * PIX + hh * 64 + qw * 4];
            *(float4*)&st[(qc * 4 + qr) * SLW + 4 + qw * 4] = v;
        }
        __syncthreads();

#pragma unroll
        for (int c = 0; c < 4; c++) {
            int cl = wid * 4 + c;
            float4 z4 = *(const float4*)&zb[(size_t)(ch + cl) * PIX + (h0 + r) * 64 + wpx];
            const float* rp = &st[(cl * 4 + r) * SLW + wpx];
            float rw[12];
            *(float4*)&rw[0] = *(const float4*)&rp[0];
            *(float4*)&rw[4] = *(const float4*)&rp[4];
            *(float4*)&rw[8] = *(const float4*)&rp[8];
            const float* zp = (const float*)&z4;
#pragma unroll
            for (int dj = 0; dj < 7; dj++)
#pragma unroll
                for (int j = 0; j < 4; j++)
                    acc[dj][j] = fmaf(zp[j], rw[j + dj + 1], acc[dj][j]);
        }
        __syncthreads();
    }

    if (wid > 0) {
#pragma unroll
        for (int dj = 0; dj < 7; dj++) {
            float4 v = make_float4(acc[dj][0], acc[dj][1], acc[dj][2], acc[dj][3]);
            *(float4*)&st[((wid - 1) * 7 + dj) * 256 + lane * 4] = v;
        }
    }
    __syncthreads();
    if (wid == 0) {
#pragma unroll
        for (int s = 0; s < 3; s++)
#pragma unroll
            for (int dj = 0; dj < 7; dj++) {
                float4 v = *(const float4*)&st[(s * 7 + dj) * 256 + lane * 4];
                acc[dj][0] += v.x; acc[dj][1] += v.y;
                acc[dj][2] += v.z; acc[dj][3] += v.w;
            }
#pragma unroll
        for (int dj = 0; dj < 7; dj++) {
            int k = di * 7 + dj;
            float4 v = make_float4(acc[dj][0], acc[dj][1], acc[dj][2], acc[dj][3]);
            *(float4*)&simb[(size_t)k * 256 + r * 64 + wpx] = v;
        }
    }
}

// ---------------------------------------------------------------------------
// K3: softmax (deferred normalization, no sv[] array) + PV with bf16 stage.
// Grid 512: bid = cqb*128 + g.  512 thr = 8 waves.
// LDS: bf16 stage 24.3 KB + bf16 unnorm-attn 25.1 KB + sinv 1 KB = 50.4 KB
//   -> 3 blocks/CU if VGPR <= 85 (no sv[25], JIT unpack keeps pressure low).
// NO launch_bounds min-wave clause (r11 lesson: it causes spill disaster).
// ---------------------------------------------------------------------------
__global__ __launch_bounds__(512) void softpv8(const float* __restrict__ sim,
                                               const float* __restrict__ x,
                                               float* __restrict__ u) {
    __shared__ __align__(16) unsigned short stb[16 * 10 * SBW]; // 24,320 B
    __shared__ __align__(16) unsigned short al[KK * 256];       // 25,088 B
    __shared__ float sinv[256];                                 // 1,024 B
    float* mred = (float*)stb;          // [2][256] alias (stage dead in softmax)
    float* sred = (float*)stb + 512;    // [2][256]

    int bid = blockIdx.x;
    int cqb = bid >> 7;          // 0..3 c-quarter
    int g   = bid & 127;
    int n   = g >> 4;
    int hq  = g & 15;
    int h0  = hq * 4;

    int tid  = threadIdx.x;
    int wid  = tid >> 6;
    int lane = tid & 63;
    int r = lane >> 4, w4 = lane & 15, wpx = w4 * 4;

    const float* simb = sim + (size_t)g * KK * 256;
    const float* xb   = x + (size_t)n * C * PIX;
    float* ub = u + (size_t)n * C * PIX;

    // ---- Phase 1: softmax, deferred norm; 2 passes over L2-resident sim ----
    {
        int ks = tid >> 8;            // 0/1
        int px = tid & 255;
        int k0 = ks ? 25 : 0;
        int nk = ks ? 24 : 25;
        float m = -1e30f;
        for (int i = 0; i < nk; i++)
            m = fmaxf(m, simb[(size_t)(k0 + i) * 256 + px]);
        mred[ks * 256 + px] = m;
        __syncthreads();
        m = fmaxf(mred[px], mred[256 + px]);
        float s = 0.f;
        for (int i = 0; i < nk; i++) {
            float e = __expf(simb[(size_t)(k0 + i) * 256 + px] - m);
            s += e;
            al[(k0 + i) * 256 + px] = (unsigned short)bf16rne(e);  // unnormalized
        }
        sred[ks * 256 + px] = s;
        __syncthreads();
        if (ks == 0) sinv[px] = 1.f / (sred[px] + sred[256 + px]);
    }
    __syncthreads();   // sinv ready; stb (mred/sred alias) reusable

    // ---- zero halo cols (0..3, 68..75) once ----
    for (int idx = tid; idx < 16 * 10 * 12; idx += 512) {
        int i12  = idx % 12;
        int rowc = idx / 12;          // c*10+row
        int col  = (i12 < 4) ? i12 : 64 + i12;
        stb[rowc * SBW + col] = 0;
    }
    // no barrier needed before stage: disjoint interior/halo regions; barrier
    // below covers visibility before reads.

    for (int ch2 = 0; ch2 < 2; ch2++) {
        int c0 = cqb * 32 + ch2 * 16;
        // ---- stage 16 c x 10 rows, bf16-packed (c-major) ----
#pragma unroll
        for (int i = 0; i < 5; i++) {
            int q  = tid + i * 512;
            int qw = q & 15, qc = (q >> 4) & 15, qr = q >> 8;
            int hh = h0 - 3 + qr;
            float4 v = make_float4(0.f, 0.f, 0.f, 0.f);
            if ((unsigned)hh < 64u)
                v = *(const float4*)&xb[(size_t)(c0 + qc) * PIX + hh * 64 + qw * 4];
            uint2 p;
            p.x = packbf(v.x, v.y);
            p.y = packbf(v.z, v.w);
            *(uint2*)&stb[(qc * 10 + qr) * SBW + 4 + qw * 4] = p;
        }
        __syncthreads();

        int cw = wid * 2;
        float u4[2][4];
#pragma unroll
        for (int cl = 0; cl < 2; cl++)
#pragma unroll
            for (int j = 0; j < 4; j++) u4[cl][j] = 0.f;

        for (int di = 0; di < 7; di++) {
#pragma unroll
            for (int cl = 0; cl < 2; cl++) {
                const unsigned short* rp = &stb[((cw + cl) * 10 + r + di) * SBW + wpx];
                uint2 q0 = *(const uint2*)&rp[0];
                uint2 q1 = *(const uint2*)&rp[4];
                uint2 q2 = *(const uint2*)&rp[8];
                float rw[12];
                rw[0]  = bflo(q0.x); rw[1]  = bfhi(q0.x);
                rw[2]  = bflo(q0.y); rw[3]  = bfhi(q0.y);
                rw[4]  = bflo(q1.x); rw[5]  = bfhi(q1.x);
                rw[6]  = bflo(q1.y); rw[7]  = bfhi(q1.y);
                rw[8]  = bflo(q2.x); rw[9]  = bfhi(q2.x);
                rw[10] = bflo(q2.y); rw[11] = bfhi(q2.y);
#pragma unroll
                for (int dj = 0; dj < 7; dj++) {
                    uint2 p = *(const uint2*)&al[(di * 7 + dj) * 256 + r * 64 + wpx];
                    float a0 = bflo(p.x), a1 = bfhi(p.x);
                    float a2 = bflo(p.y), a3 = bfhi(p.y);
                    u4[cl][0] = fmaf(a0, rw[dj + 1], u4[cl][0]);
                    u4[cl][1] = fmaf(a1, rw[dj + 2], u4[cl][1]);
                    u4[cl][2] = fmaf(a2, rw[dj + 3], u4[cl][2]);
                    u4[cl][3] = fmaf(a3, rw[dj + 4], u4[cl][3]);
                }
            }
        }

        // ---- epilogue: apply deferred 1/S, write ----
        float4 s4 = *(const float4*)&sinv[r * 64 + wpx];
        const float* sp = (const float*)&s4;
#pragma unroll
        for (int cl = 0; cl < 2; cl++) {
            int c = c0 + cw + cl;
            float4 v = make_float4(u4[cl][0] * sp[0], u4[cl][1] * sp[1],
                                   u4[cl][2] * sp[2], u4[cl][3] * sp[3]);
            *(float4*)&ub[(size_t)c * PIX + (h0 + r) * 64 + wpx] = v;
        }
        __syncthreads();
    }
}

// ---------------------------------------------------------------------------
extern "C" void kernel_launch(void* const* d_in, const int* in_sizes, int n_in,
                              void* d_out, int out_size, void* d_ws, size_t ws_size,
                              hipStream_t stream) {
    const float* x  = (const float*)d_in[0];
    const float* w1 = (const float*)d_in[1];
    const float* w2 = (const float*)d_in[2];
    const float* w3 = (const float*)d_in[3];
    float* wsf = (float*)d_ws;

    prep<<<68, 256, 0, stream>>>(w1, w2, w3, wsf + M_OFF, wsf + WT3_OFF);
    convk<<<512, 256, 0, stream>>>(wsf + M_OFF, x, wsf + Z_OFF);               // z = M^T x
    simk2<<<896, 256, 0, stream>>>(wsf + Z_OFF, x, wsf + SIM_OFF);             // sim
    softpv8<<<512, 512, 0, stream>>>(wsf + SIM_OFF, x, wsf + U_OFF);           // softmax+PV
    convk<<<512, 256, 0, stream>>>(wsf + WT3_OFF, wsf + U_OFF, (float*)d_out); // out = W3 u
}

// Round 15
// 97.145 us; speedup vs baseline: 2.8773x; 1.1769x over previous
//
#include <hip/hip_runtime.h>
#include <math.h>

// Problem constants
constexpr int N = 8, C = 128, H = 64, W = 64;
constexpr int PIX = H * W;            // 4096
constexpr int KK = 49;                // 7x7 window

// ws layout (floats) — first 32768 floats hold 4 bf16 A-matrices (hi/lo x 2)
constexpr size_t Z_OFF   = 65536;                    // z = M^T x
constexpr size_t YSZ     = (size_t)N * C * PIX;      // 4,194,304
constexpr size_t SIM_OFF = Z_OFF + YSZ;              // sim fp32 [g=128][49][256]
constexpr size_t SIMSZ   = (size_t)N * 16 * KK * 256;// 1,605,632
constexpr size_t U_OFF   = SIM_OFF + SIMSZ;          // u = PV(x)

constexpr int SLW = 76;   // fp32 stage row width (simk2)
constexpr int SBW = 76;   // bf16 stage row width in ushorts (softpv8)
constexpr int ALW = 136;  // convm LDS row stride (ushorts): 272B ≡ +4 banks/row

typedef __attribute__((ext_vector_type(8))) short bf16x8;
typedef __attribute__((ext_vector_type(4))) float f32x4;

__device__ __forceinline__ unsigned bf16rne(float f) {
    unsigned u = __float_as_uint(f);
    u += 0x7FFFu + ((u >> 16) & 1u);
    return u >> 16;
}
__device__ __forceinline__ unsigned packbf(float a, float b) {
    return bf16rne(a) | (bf16rne(b) << 16);
}
__device__ __forceinline__ float bflo(unsigned u) { return __uint_as_float(u << 16); }
__device__ __forceinline__ float bfhi(unsigned u) { return __uint_as_float(u & 0xFFFF0000u); }

// ---------------------------------------------------------------------------
// K0: prep.  Blocks 0..63: M[a][b] -> A1hi/A1lo at [b*128+a]  (A1[oc=b][k=a]).
//            Blocks 64..67: w3 -> A2hi/A2lo at [o*128+c]      (A2[oc=o][k=c]).
// hi = bf16(v); lo = bf16(v - hi): 3-pass MFMA gives fp32-quality product.
// ---------------------------------------------------------------------------
__global__ __launch_bounds__(256) void prep(const float* __restrict__ w1,
                                            const float* __restrict__ w2,
                                            const float* __restrict__ w3,
                                            unsigned short* __restrict__ A1hi,
                                            unsigned short* __restrict__ A1lo,
                                            unsigned short* __restrict__ A2hi,
                                            unsigned short* __restrict__ A2lo) {
    int bid = blockIdx.x, tid = threadIdx.x;
    if (bid < 64) {
        int a = bid * 2 + (tid >> 7);
        int b = tid & 127;
        float s = 0.f;
        for (int c = 0; c < 128; c++)
            s = fmaf(w1[c * 128 + a], w2[c * 128 + b], s);
        unsigned h = bf16rne(s);
        float lo = s - __uint_as_float(h << 16);
        A1hi[b * 128 + a] = (unsigned short)h;
        A1lo[b * 128 + a] = (unsigned short)bf16rne(lo);
    } else {
        int base = (bid - 64) * 4096;
        for (int i = tid; i < 4096; i += 256) {
            int idx = base + i;
            float v = w3[idx];
            unsigned h = bf16rne(v);
            float lo = v - __uint_as_float(h << 16);
            A2hi[idx] = (unsigned short)h;
            A2lo[idx] = (unsigned short)bf16rne(lo);
        }
    }
}

// ---------------------------------------------------------------------------
// K1: split-precision MFMA 1x1-conv.  Y = A*B per image, A 128x128, B 128x64px.
// Grid 512 = n(8) x px-tile(64).  256 thr = 4 waves.
// LDS: xT hi/lo only (34.8 KB -> 4 blocks/CU);  A fragments read from global
// (32 KB, L2-hot, reused 64x per row).
// 3-pass: acc += Ah*Bh + Ah*Bl + Al*Bh  (dropped Al*Bl ~ 2^-16 rel).
// Fragment layouts as validated in r14 (correct, only precision failed).
// ---------------------------------------------------------------------------
__global__ __launch_bounds__(256) void convm(const unsigned short* __restrict__ Ahi,
                                             const unsigned short* __restrict__ Alo,
                                             const float* __restrict__ Bsrc,
                                             float* __restrict__ Yout) {
    __shared__ __align__(16) unsigned short xh[64 * ALW];   // 17,408 B
    __shared__ __align__(16) unsigned short xl[64 * ALW];   // 17,408 B

    int bid = blockIdx.x;
    int pt  = bid & 63;
    int n   = bid >> 6;
    int p0  = pt * 64;

    const float* B = Bsrc + (size_t)n * C * PIX;
    float*       Y = Yout + (size_t)n * C * PIX;

    int tid  = threadIdx.x;
    int wid  = tid >> 6;
    int lane = tid & 63;
    int l15  = lane & 15;
    int lg   = lane >> 4;          // 0..3 k-group

    // ---- stage x-tile transposed, hi/lo bf16 packed pairs ----
    unsigned* xhd = (unsigned*)xh;           // row stride 68 dwords
    unsigned* xld = (unsigned*)xl;
#pragma unroll
    for (int i = 0; i < 4; i++) {
        int q  = tid + i * 256;
        int cp = q >> 4;                     // 0..63 channel pair
        int f  = q & 15;                     // f4 index (4 px)
        float4 va = *(const float4*)&B[(size_t)(2 * cp) * PIX + p0 + f * 4];
        float4 vb = *(const float4*)&B[(size_t)(2 * cp + 1) * PIX + p0 + f * 4];
        const float* pa = (const float*)&va;
        const float* pb = (const float*)&vb;
#pragma unroll
        for (int j = 0; j < 4; j++) {
            unsigned ha = bf16rne(pa[j]);
            unsigned hb = bf16rne(pb[j]);
            float la = pa[j] - __uint_as_float(ha << 16);
            float lb = pb[j] - __uint_as_float(hb << 16);
            xhd[(f * 4 + j) * 68 + cp] = ha | (hb << 16);
            xld[(f * 4 + j) * 68 + cp] = bf16rne(la) | (bf16rne(lb) << 16);
        }
    }
    __syncthreads();

    // ---- MFMA main: wave owns oc0 = wid*32, all 4 px-tiles ----
    f32x4 acc[2][4];
#pragma unroll
    for (int t = 0; t < 2; t++)
#pragma unroll
        for (int p = 0; p < 4; p++) acc[t][p] = (f32x4){0.f, 0.f, 0.f, 0.f};

#pragma unroll
    for (int kc = 0; kc < 4; kc++) {
        int k0 = kc * 32 + lg * 8;
        bf16x8 ah[2], al_[2], bh[4], bl[4];
#pragma unroll
        for (int t = 0; t < 2; t++) {
            int row = wid * 32 + t * 16 + l15;
            ah[t]  = *(const bf16x8*)&Ahi[row * 128 + k0];
            al_[t] = *(const bf16x8*)&Alo[row * 128 + k0];
        }
#pragma unroll
        for (int p = 0; p < 4; p++) {
            bh[p] = *(const bf16x8*)&xh[(p * 16 + l15) * ALW + k0];
            bl[p] = *(const bf16x8*)&xl[(p * 16 + l15) * ALW + k0];
        }
#pragma unroll
        for (int t = 0; t < 2; t++)
#pragma unroll
            for (int p = 0; p < 4; p++) {
                acc[t][p] = __builtin_amdgcn_mfma_f32_16x16x32_bf16(
                    ah[t], bh[p], acc[t][p], 0, 0, 0);
                acc[t][p] = __builtin_amdgcn_mfma_f32_16x16x32_bf16(
                    ah[t], bl[p], acc[t][p], 0, 0, 0);
                acc[t][p] = __builtin_amdgcn_mfma_f32_16x16x32_bf16(
                    al_[t], bh[p], acc[t][p], 0, 0, 0);
            }
    }

    // ---- epilogue: D row=(lg*4+reg), col=l15 ----
#pragma unroll
    for (int t = 0; t < 2; t++) {
#pragma unroll
        for (int p = 0; p < 4; p++) {
#pragma unroll
            for (int reg = 0; reg < 4; reg++) {
                int oc = wid * 32 + t * 16 + lg * 4 + reg;
                int px = p0 + p * 16 + l15;
                Y[(size_t)oc * PIX + px] = acc[t][p][reg];
            }
        }
    }
}

// ---------------------------------------------------------------------------
// K2: sim[g][k][px], ONE di PER BLOCK.  (r7 simk2 — measured best, unchanged)
// ---------------------------------------------------------------------------
__global__ __launch_bounds__(256) void simk2(const float* __restrict__ z,
                                             const float* __restrict__ x,
                                             float* __restrict__ sim) {
    __shared__ __align__(16) float st[5376];

    int bid = blockIdx.x;
    int di  = bid >> 7;
    int g   = bid & 127;
    int n   = g >> 4;
    int hq  = g & 15;
    int h0  = hq * 4;

    int tid  = threadIdx.x;
    int wid  = tid >> 6;
    int lane = tid & 63;
    int r = lane >> 4, w4 = lane & 15, wpx = w4 * 4;

    const float* zb = z + (size_t)n * C * PIX;
    const float* xb = x + (size_t)n * C * PIX;
    float* simb = sim + ((size_t)g * KK) * 256;

    for (int idx = tid; idx < 16 * 4 * 8; idx += 256) {
        int col8 = idx & 7;
        int row  = (idx >> 3) & 3;
        int c    = idx >> 5;
        int col  = (col8 < 4) ? col8 : 64 + col8;
        st[(c * 4 + row) * SLW + col] = 0.f;
    }
    __syncthreads();

    float acc[7][4];
#pragma unroll
    for (int dj = 0; dj < 7; dj++)
#pragma unroll
        for (int j = 0; j < 4; j++) acc[dj][j] = 0.f;

    for (int ch = 0; ch < C; ch += 16) {
#pragma unroll
        for (int i = 0; i < 4; i++) {
            int q  = tid + i * 256;
            int qw = q & 15, qc = (q >> 4) & 15, qr = q >> 8;
            int hh = h0 + di - 3 + qr;
            float4 v = make_float4(0.f, 0.f, 0.f, 0.f);
            if ((unsigned)hh < 64u)
                v = *(const float4*)&xb[(size_t)(ch + qc) * PIX + hh * 64 + qw * 4];
            *(float4*)&st[(qc * 4 + qr) * SLW + 4 + qw * 4] = v;
        }
        __syncthreads();

#pragma unroll
        for (int c = 0; c < 4; c++) {
            int cl = wid * 4 + c;
            float4 z4 = *(const float4*)&zb[(size_t)(ch + cl) * PIX + (h0 + r) * 64 + wpx];
            const float* rp = &st[(cl * 4 + r) * SLW + wpx];
            float rw[12];
            *(float4*)&rw[0] = *(const float4*)&rp[0];
            *(float4*)&rw[4] = *(const float4*)&rp[4];
            *(float4*)&rw[8] = *(const float4*)&rp[8];
            const float* zp = (const float*)&z4;
#pragma unroll
            for (int dj = 0; dj < 7; dj++)
#pragma unroll
                for (int j = 0; j < 4; j++)
                    acc[dj][j] = fmaf(zp[j], rw[j + dj + 1], acc[dj][j]);
        }
        __syncthreads();
    }

    if (wid > 0) {
#pragma unroll
        for (int dj = 0; dj < 7; dj++) {
            float4 v = make_float4(acc[dj][0], acc[dj][1], acc[dj][2], acc[dj][3]);
            *(float4*)&st[((wid - 1) * 7 + dj) * 256 + lane * 4] = v;
        }
    }
    __syncthreads();
    if (wid == 0) {
#pragma unroll
        for (int s = 0; s < 3; s++)
#pragma unroll
            for (int dj = 0; dj < 7; dj++) {
                float4 v = *(const float4*)&st[(s * 7 + dj) * 256 + lane * 4];
                acc[dj][0] += v.x; acc[dj][1] += v.y;
                acc[dj][2] += v.z; acc[dj][3] += v.w;
            }
#pragma unroll
        for (int dj = 0; dj < 7; dj++) {
            int k = di * 7 + dj;
            float4 v = make_float4(acc[dj][0], acc[dj][1], acc[dj][2], acc[dj][3]);
            *(float4*)&simb[(size_t)k * 256 + r * 64 + wpx] = v;
        }
    }
}

// ---------------------------------------------------------------------------
// K3: softmax (deferred normalization) + PV with bf16 stage.  (r13, unchanged)
// ---------------------------------------------------------------------------
__global__ __launch_bounds__(512) void softpv8(const float* __restrict__ sim,
                                               const float* __restrict__ x,
                                               float* __restrict__ u) {
    __shared__ __align__(16) unsigned short stb[16 * 10 * SBW]; // 24,320 B
    __shared__ __align__(16) unsigned short al[KK * 256];       // 25,088 B
    __shared__ float sinv[256];                                 // 1,024 B
    float* mred = (float*)stb;
    float* sred = (float*)stb + 512;

    int bid = blockIdx.x;
    int cqb = bid >> 7;
    int g   = bid & 127;
    int n   = g >> 4;
    int hq  = g & 15;
    int h0  = hq * 4;

    int tid  = threadIdx.x;
    int wid  = tid >> 6;
    int lane = tid & 63;
    int r = lane >> 4, w4 = lane & 15, wpx = w4 * 4;

    const float* simb = sim + (size_t)g * KK * 256;
    const float* xb   = x + (size_t)n * C * PIX;
    float* ub = u + (size_t)n * C * PIX;

    {
        int ks = tid >> 8;
        int px = tid & 255;
        int k0 = ks ? 25 : 0;
        int nk = ks ? 24 : 25;
        float m = -1e30f;
        for (int i = 0; i < nk; i++)
            m = fmaxf(m, simb[(size_t)(k0 + i) * 256 + px]);
        mred[ks * 256 + px] = m;
        __syncthreads();
        m = fmaxf(mred[px], mred[256 + px]);
        float s = 0.f;
        for (int i = 0; i < nk; i++) {
            float e = __expf(simb[(size_t)(k0 + i) * 256 + px] - m);
            s += e;
            al[(k0 + i) * 256 + px] = (unsigned short)bf16rne(e);
        }
        sred[ks * 256 + px] = s;
        __syncthreads();
        if (ks == 0) sinv[px] = 1.f / (sred[px] + sred[256 + px]);
    }
    __syncthreads();

    for (int idx = tid; idx < 16 * 10 * 12; idx += 512) {
        int i12  = idx % 12;
        int rowc = idx / 12;
        int col  = (i12 < 4) ? i12 : 64 + i12;
        stb[rowc * SBW + col] = 0;
    }

    for (int ch2 = 0; ch2 < 2; ch2++) {
        int c0 = cqb * 32 + ch2 * 16;
#pragma unroll
        for (int i = 0; i < 5; i++) {
            int q  = tid + i * 512;
            int qw = q & 15, qc = (q >> 4) & 15, qr = q >> 8;
            int hh = h0 - 3 + qr;
            float4 v = make_float4(0.f, 0.f, 0.f, 0.f);
            if ((unsigned)hh < 64u)
                v = *(const float4*)&xb[(size_t)(c0 + qc) * PIX + hh * 64 + qw * 4];
            uint2 p;
            p.x = packbf(v.x, v.y);
            p.y = packbf(v.z, v.w);
            *(uint2*)&stb[(qc * 10 + qr) * SBW + 4 + qw * 4] = p;
        }
        __syncthreads();

        int cw = wid * 2;
        float u4[2][4];
#pragma unroll
        for (int cl = 0; cl < 2; cl++)
#pragma unroll
            for (int j = 0; j < 4; j++) u4[cl][j] = 0.f;

        for (int di = 0; di < 7; di++) {
#pragma unroll
            for (int cl = 0; cl < 2; cl++) {
                const unsigned short* rp = &stb[((cw + cl) * 10 + r + di) * SBW + wpx];
                uint2 q0 = *(const uint2*)&rp[0];
                uint2 q1 = *(const uint2*)&rp[4];
                uint2 q2 = *(const uint2*)&rp[8];
                float rw[12];
                rw[0]  = bflo(q0.x); rw[1]  = bfhi(q0.x);
                rw[2]  = bflo(q0.y); rw[3]  = bfhi(q0.y);
                rw[4]  = bflo(q1.x); rw[5]  = bfhi(q1.x);
                rw[6]  = bflo(q1.y); rw[7]  = bfhi(q1.y);
                rw[8]  = bflo(q2.x); rw[9]  = bfhi(q2.x);
                rw[10] = bflo(q2.y); rw[11] = bfhi(q2.y);
#pragma unroll
                for (int dj = 0; dj < 7; dj++) {
                    uint2 p = *(const uint2*)&al[(di * 7 + dj) * 256 + r * 64 + wpx];
                    float a0 = bflo(p.x), a1 = bfhi(p.x);
                    float a2 = bflo(p.y), a3 = bfhi(p.y);
                    u4[cl][0] = fmaf(a0, rw[dj + 1], u4[cl][0]);
                    u4[cl][1] = fmaf(a1, rw[dj + 2], u4[cl][1]);
                    u4[cl][2] = fmaf(a2, rw[dj + 3], u4[cl][2]);
                    u4[cl][3] = fmaf(a3, rw[dj + 4], u4[cl][3]);
                }
            }
        }

        float4 s4 = *(const float4*)&sinv[r * 64 + wpx];
        const float* sp = (const float*)&s4;
#pragma unroll
        for (int cl = 0; cl < 2; cl++) {
            int c = c0 + cw + cl;
            float4 v = make_float4(u4[cl][0] * sp[0], u4[cl][1] * sp[1],
                                   u4[cl][2] * sp[2], u4[cl][3] * sp[3]);
            *(float4*)&ub[(size_t)c * PIX + (h0 + r) * 64 + wpx] = v;
        }
        __syncthreads();
    }
}

// ---------------------------------------------------------------------------
extern "C" void kernel_launch(void* const* d_in, const int* in_sizes, int n_in,
                              void* d_out, int out_size, void* d_ws, size_t ws_size,
                              hipStream_t stream) {
    const float* x  = (const float*)d_in[0];
    const float* w1 = (const float*)d_in[1];
    const float* w2 = (const float*)d_in[2];
    const float* w3 = (const float*)d_in[3];
    float* wsf = (float*)d_ws;
    unsigned short* A1hi = (unsigned short*)wsf;          // 16384 ushorts each
    unsigned short* A1lo = A1hi + 16384;
    unsigned short* A2hi = A1hi + 32768;
    unsigned short* A2lo = A1hi + 49152;

    prep<<<68, 256, 0, stream>>>(w1, w2, w3, A1hi, A1lo, A2hi, A2lo);
    convm<<<512, 256, 0, stream>>>(A1hi, A1lo, x, wsf + Z_OFF);            // z
    simk2<<<896, 256, 0, stream>>>(wsf + Z_OFF, x, wsf + SIM_OFF);         // sim
    softpv8<<<512, 512, 0, stream>>>(wsf + SIM_OFF, x, wsf + U_OFF);       // softmax+PV
    convm<<<512, 256, 0, stream>>>(A2hi, A2lo, wsf + U_OFF, (float*)d_out); // out
}

// Round 16
// 94.449 us; speedup vs baseline: 2.9594x; 1.0285x over previous
//
#include <hip/hip_runtime.h>
#include <math.h>

// Problem constants
constexpr int N = 8, C = 128, H = 64, W = 64;
constexpr int PIX = H * W;            // 4096
constexpr int KK = 49;                // 7x7 window

// ws layout (floats) — first 32768 floats hold 4 bf16 A-matrices (hi/lo x 2)
constexpr size_t Z_OFF   = 65536;                    // z = M^T x
constexpr size_t YSZ     = (size_t)N * C * PIX;      // 4,194,304
constexpr size_t SIM_OFF = Z_OFF + YSZ;              // sim fp32 [g=128][49][256]
constexpr size_t SIMSZ   = (size_t)N * 16 * KK * 256;// 1,605,632
constexpr size_t U_OFF   = SIM_OFF + SIMSZ;          // u = PV(x)

constexpr int SLW = 76;   // fp32 stage row width (simk6)
constexpr int SBW = 76;   // bf16 stage row width in ushorts (softpv8)
constexpr int ALW = 136;  // convm LDS row stride (ushorts)

typedef __attribute__((ext_vector_type(8))) short bf16x8;
typedef __attribute__((ext_vector_type(4))) float f32x4;

__device__ __forceinline__ unsigned bf16rne(float f) {
    unsigned u = __float_as_uint(f);
    u += 0x7FFFu + ((u >> 16) & 1u);
    return u >> 16;
}
__device__ __forceinline__ unsigned packbf(float a, float b) {
    return bf16rne(a) | (bf16rne(b) << 16);
}
__device__ __forceinline__ float bflo(unsigned u) { return __uint_as_float(u << 16); }
__device__ __forceinline__ float bfhi(unsigned u) { return __uint_as_float(u & 0xFFFF0000u); }

// ---------------------------------------------------------------------------
// K0: prep — M = W1^T W2 -> A1 hi/lo bf16; W3 -> A2 hi/lo bf16.  (r15)
// ---------------------------------------------------------------------------
__global__ __launch_bounds__(256) void prep(const float* __restrict__ w1,
                                            const float* __restrict__ w2,
                                            const float* __restrict__ w3,
                                            unsigned short* __restrict__ A1hi,
                                            unsigned short* __restrict__ A1lo,
                                            unsigned short* __restrict__ A2hi,
                                            unsigned short* __restrict__ A2lo) {
    int bid = blockIdx.x, tid = threadIdx.x;
    if (bid < 64) {
        int a = bid * 2 + (tid >> 7);
        int b = tid & 127;
        float s = 0.f;
        for (int c = 0; c < 128; c++)
            s = fmaf(w1[c * 128 + a], w2[c * 128 + b], s);
        unsigned h = bf16rne(s);
        float lo = s - __uint_as_float(h << 16);
        A1hi[b * 128 + a] = (unsigned short)h;
        A1lo[b * 128 + a] = (unsigned short)bf16rne(lo);
    } else {
        int base = (bid - 64) * 4096;
        for (int i = tid; i < 4096; i += 256) {
            int idx = base + i;
            float v = w3[idx];
            unsigned h = bf16rne(v);
            float lo = v - __uint_as_float(h << 16);
            A2hi[idx] = (unsigned short)h;
            A2lo[idx] = (unsigned short)bf16rne(lo);
        }
    }
}

// ---------------------------------------------------------------------------
// K1: split-precision MFMA 1x1-conv (r15, measured-good, unchanged).
// ---------------------------------------------------------------------------
__global__ __launch_bounds__(256) void convm(const unsigned short* __restrict__ Ahi,
                                             const unsigned short* __restrict__ Alo,
                                             const float* __restrict__ Bsrc,
                                             float* __restrict__ Yout) {
    __shared__ __align__(16) unsigned short xh[64 * ALW];
    __shared__ __align__(16) unsigned short xl[64 * ALW];

    int bid = blockIdx.x;
    int pt  = bid & 63;
    int n   = bid >> 6;
    int p0  = pt * 64;

    const float* B = Bsrc + (size_t)n * C * PIX;
    float*       Y = Yout + (size_t)n * C * PIX;

    int tid  = threadIdx.x;
    int wid  = tid >> 6;
    int lane = tid & 63;
    int l15  = lane & 15;
    int lg   = lane >> 4;

    unsigned* xhd = (unsigned*)xh;
    unsigned* xld = (unsigned*)xl;
#pragma unroll
    for (int i = 0; i < 4; i++) {
        int q  = tid + i * 256;
        int cp = q >> 4;
        int f  = q & 15;
        float4 va = *(const float4*)&B[(size_t)(2 * cp) * PIX + p0 + f * 4];
        float4 vb = *(const float4*)&B[(size_t)(2 * cp + 1) * PIX + p0 + f * 4];
        const float* pa = (const float*)&va;
        const float* pb = (const float*)&vb;
#pragma unroll
        for (int j = 0; j < 4; j++) {
            unsigned ha = bf16rne(pa[j]);
            unsigned hb = bf16rne(pb[j]);
            float la = pa[j] - __uint_as_float(ha << 16);
            float lb = pb[j] - __uint_as_float(hb << 16);
            xhd[(f * 4 + j) * 68 + cp] = ha | (hb << 16);
            xld[(f * 4 + j) * 68 + cp] = bf16rne(la) | (bf16rne(lb) << 16);
        }
    }
    __syncthreads();

    f32x4 acc[2][4];
#pragma unroll
    for (int t = 0; t < 2; t++)
#pragma unroll
        for (int p = 0; p < 4; p++) acc[t][p] = (f32x4){0.f, 0.f, 0.f, 0.f};

#pragma unroll
    for (int kc = 0; kc < 4; kc++) {
        int k0 = kc * 32 + lg * 8;
        bf16x8 ah[2], al_[2], bh[4], bl[4];
#pragma unroll
        for (int t = 0; t < 2; t++) {
            int row = wid * 32 + t * 16 + l15;
            ah[t]  = *(const bf16x8*)&Ahi[row * 128 + k0];
            al_[t] = *(const bf16x8*)&Alo[row * 128 + k0];
        }
#pragma unroll
        for (int p = 0; p < 4; p++) {
            bh[p] = *(const bf16x8*)&xh[(p * 16 + l15) * ALW + k0];
            bl[p] = *(const bf16x8*)&xl[(p * 16 + l15) * ALW + k0];
        }
#pragma unroll
        for (int t = 0; t < 2; t++)
#pragma unroll
            for (int p = 0; p < 4; p++) {
                acc[t][p] = __builtin_amdgcn_mfma_f32_16x16x32_bf16(
                    ah[t], bh[p], acc[t][p], 0, 0, 0);
                acc[t][p] = __builtin_amdgcn_mfma_f32_16x16x32_bf16(
                    ah[t], bl[p], acc[t][p], 0, 0, 0);
                acc[t][p] = __builtin_amdgcn_mfma_f32_16x16x32_bf16(
                    al_[t], bh[p], acc[t][p], 0, 0, 0);
            }
    }

#pragma unroll
    for (int t = 0; t < 2; t++) {
#pragma unroll
        for (int p = 0; p < 4; p++) {
#pragma unroll
            for (int reg = 0; reg < 4; reg++) {
                int oc = wid * 32 + t * 16 + lg * 4 + reg;
                int px = p0 + p * 16 + l15;
                Y[(size_t)oc * PIX + px] = acc[t][p][reg];
            }
        }
    }
}

// ---------------------------------------------------------------------------
// K2: simk6 — simk2 + T14 async-stage split + z one-chunk-ahead prefetch.
// Fully unrolled ch loop; xs/zs ping-pong via ch&1 (compile-time, no scratch).
// Next-chunk global loads issue BEFORE the stage-visible barrier -> latency
// overlaps current chunk's compute.  Same barriers/LDS/math as simk2.
// ---------------------------------------------------------------------------
__global__ __launch_bounds__(256) void simk6(const float* __restrict__ z,
                                             const float* __restrict__ x,
                                             float* __restrict__ sim) {
    __shared__ __align__(16) float st[5376];  // stage 16*4*76=4864 | red 5376

    int bid = blockIdx.x;
    int di  = bid >> 7;
    int g   = bid & 127;
    int n   = g >> 4;
    int hq  = g & 15;
    int h0  = hq * 4;

    int tid  = threadIdx.x;
    int wid  = tid >> 6;
    int lane = tid & 63;
    int r = lane >> 4, w4 = lane & 15, wpx = w4 * 4;
    int qw = tid & 15, qc = (tid >> 4) & 15;   // staging role: fixed (qw,qc), rows 0..3

    const float* zb = z + (size_t)n * C * PIX;
    const float* xb = x + (size_t)n * C * PIX;
    float* simb = sim + ((size_t)g * KK) * 256;

    // halo zero (visible to compute via first stage barrier)
    for (int idx = tid; idx < 16 * 4 * 8; idx += 256) {
        int col8 = idx & 7;
        int row  = (idx >> 3) & 3;
        int c    = idx >> 5;
        int col  = (col8 < 4) ? col8 : 64 + col8;
        st[(c * 4 + row) * SLW + col] = 0.f;
    }

    float acc[7][4];
#pragma unroll
    for (int dj = 0; dj < 7; dj++)
#pragma unroll
        for (int j = 0; j < 4; j++) acc[dj][j] = 0.f;

    int hh0 = h0 + di - 3;
    float4 xs[2][4], zs[2][4];

    // prologue: issue chunk-0 loads
#pragma unroll
    for (int i = 0; i < 4; i++) {
        int hh = hh0 + i;
        float4 v = make_float4(0.f, 0.f, 0.f, 0.f);
        if ((unsigned)hh < 64u)
            v = *(const float4*)&xb[(size_t)qc * PIX + hh * 64 + qw * 4];
        xs[0][i] = v;
    }
#pragma unroll
    for (int c = 0; c < 4; c++)
        zs[0][c] = *(const float4*)&zb[(size_t)(wid * 4 + c) * PIX + (h0 + r) * 64 + wpx];

#pragma unroll
    for (int ch = 0; ch < 8; ch++) {
        int cur = ch & 1, nxt = cur ^ 1;           // compile-time after unroll
        // write staged regs to LDS (prev compute already barrier-drained)
#pragma unroll
        for (int i = 0; i < 4; i++)
            *(float4*)&st[(qc * 4 + i) * SLW + 4 + qw * 4] = xs[cur][i];
        // issue NEXT chunk's global loads (latency hides under compute below)
        if (ch < 7) {
            int cb = (ch + 1) * 16;
#pragma unroll
            for (int i = 0; i < 4; i++) {
                int hh = hh0 + i;
                float4 v = make_float4(0.f, 0.f, 0.f, 0.f);
                if ((unsigned)hh < 64u)
                    v = *(const float4*)&xb[(size_t)(cb + qc) * PIX + hh * 64 + qw * 4];
                xs[nxt][i] = v;
            }
#pragma unroll
            for (int c = 0; c < 4; c++)
                zs[nxt][c] = *(const float4*)&zb[(size_t)(cb + wid * 4 + c) * PIX
                                                 + (h0 + r) * 64 + wpx];
        }
        __syncthreads();   // stage visible

        // compute chunk ch (pure LDS + FMA; z already in registers)
#pragma unroll
        for (int c = 0; c < 4; c++) {
            int cl = wid * 4 + c;
            const float* rp = &st[(cl * 4 + r) * SLW + wpx];
            float rw[12];
            *(float4*)&rw[0] = *(const float4*)&rp[0];
            *(float4*)&rw[4] = *(const float4*)&rp[4];
            *(float4*)&rw[8] = *(const float4*)&rp[8];
            const float* zp = (const float*)&zs[cur][c];
#pragma unroll
            for (int dj = 0; dj < 7; dj++)
#pragma unroll
                for (int j = 0; j < 4; j++)
                    acc[dj][j] = fmaf(zp[j], rw[j + dj + 1], acc[dj][j]);
        }
        __syncthreads();   // compute done; next iteration may overwrite LDS
    }

    // cross-wave reduce (st aliased as red buffer)
    if (wid > 0) {
#pragma unroll
        for (int dj = 0; dj < 7; dj++) {
            float4 v = make_float4(acc[dj][0], acc[dj][1], acc[dj][2], acc[dj][3]);
            *(float4*)&st[((wid - 1) * 7 + dj) * 256 + lane * 4] = v;
        }
    }
    __syncthreads();
    if (wid == 0) {
#pragma unroll
        for (int s = 0; s < 3; s++)
#pragma unroll
            for (int dj = 0; dj < 7; dj++) {
                float4 v = *(const float4*)&st[(s * 7 + dj) * 256 + lane * 4];
                acc[dj][0] += v.x; acc[dj][1] += v.y;
                acc[dj][2] += v.z; acc[dj][3] += v.w;
            }
#pragma unroll
        for (int dj = 0; dj < 7; dj++) {
            int k = di * 7 + dj;
            float4 v = make_float4(acc[dj][0], acc[dj][1], acc[dj][2], acc[dj][3]);
            *(float4*)&simb[(size_t)k * 256 + r * 64 + wpx] = v;
        }
    }
}

// ---------------------------------------------------------------------------
// K3: softmax (deferred normalization) + PV with bf16 stage.  (r13, unchanged)
// ---------------------------------------------------------------------------
__global__ __launch_bounds__(512) void softpv8(const float* __restrict__ sim,
                                               const float* __restrict__ x,
                                               float* __restrict__ u) {
    __shared__ __align__(16) unsigned short stb[16 * 10 * SBW];
    __shared__ __align__(16) unsigned short al[KK * 256];
    __shared__ float sinv[256];
    float* mred = (float*)stb;
    float* sred = (float*)stb + 512;

    int bid = blockIdx.x;
    int cqb = bid >> 7;
    int g   = bid & 127;
    int n   = g >> 4;
    int hq  = g & 15;
    int h0  = hq * 4;

    int tid  = threadIdx.x;
    int wid  = tid >> 6;
    int lane = tid & 63;
    int r = lane >> 4, w4 = lane & 15, wpx = w4 * 4;

    const float* simb = sim + (size_t)g * KK * 256;
    const float* xb   = x + (size_t)n * C * PIX;
    float* ub = u + (size_t)n * C * PIX;

    {
        int ks = tid >> 8;
        int px = tid & 255;
        int k0 = ks ? 25 : 0;
        int nk = ks ? 24 : 25;
        float m = -1e30f;
        for (int i = 0; i < nk; i++)
            m = fmaxf(m, simb[(size_t)(k0 + i) * 256 + px]);
        mred[ks * 256 + px] = m;
        __syncthreads();
        m = fmaxf(mred[px], mred[256 + px]);
        float s = 0.f;
        for (int i = 0; i < nk; i++) {
            float e = __expf(simb[(size_t)(k0 + i) * 256 + px] - m);
            s += e;
            al[(k0 + i) * 256 + px] = (unsigned short)bf16rne(e);
        }
        sred[ks * 256 + px] = s;
        __syncthreads();
        if (ks == 0) sinv[px] = 1.f / (sred[px] + sred[256 + px]);
    }
    __syncthreads();

    for (int idx = tid; idx < 16 * 10 * 12; idx += 512) {
        int i12  = idx % 12;
        int rowc = idx / 12;
        int col  = (i12 < 4) ? i12 : 64 + i12;
        stb[rowc * SBW + col] = 0;
    }

    for (int ch2 = 0; ch2 < 2; ch2++) {
        int c0 = cqb * 32 + ch2 * 16;
#pragma unroll
        for (int i = 0; i < 5; i++) {
            int q  = tid + i * 512;
            int qw = q & 15, qc = (q >> 4) & 15, qr = q >> 8;
            int hh = h0 - 3 + qr;
            float4 v = make_float4(0.f, 0.f, 0.f, 0.f);
            if ((unsigned)hh < 64u)
                v = *(const float4*)&xb[(size_t)(c0 + qc) * PIX + hh * 64 + qw * 4];
            uint2 p;
            p.x = packbf(v.x, v.y);
            p.y = packbf(v.z, v.w);
            *(uint2*)&stb[(qc * 10 + qr) * SBW + 4 + qw * 4] = p;
        }
        __syncthreads();

        int cw = wid * 2;
        float u4[2][4];
#pragma unroll
        for (int cl = 0; cl < 2; cl++)
#pragma unroll
            for (int j = 0; j < 4; j++) u4[cl][j] = 0.f;

        for (int di = 0; di < 7; di++) {
#pragma unroll
            for (int cl = 0; cl < 2; cl++) {
                const unsigned short* rp = &stb[((cw + cl) * 10 + r + di) * SBW + wpx];
                uint2 q0 = *(const uint2*)&rp[0];
                uint2 q1 = *(const uint2*)&rp[4];
                uint2 q2 = *(const uint2*)&rp[8];
                float rw[12];
                rw[0]  = bflo(q0.x); rw[1]  = bfhi(q0.x);
                rw[2]  = bflo(q0.y); rw[3]  = bfhi(q0.y);
                rw[4]  = bflo(q1.x); rw[5]  = bfhi(q1.x);
                rw[6]  = bflo(q1.y); rw[7]  = bfhi(q1.y);
                rw[8]  = bflo(q2.x); rw[9]  = bfhi(q2.x);
                rw[10] = bflo(q2.y); rw[11] = bfhi(q2.y);
#pragma unroll
                for (int dj = 0; dj < 7; dj++) {
                    uint2 p = *(const uint2*)&al[(di * 7 + dj) * 256 + r * 64 + wpx];
                    float a0 = bflo(p.x), a1 = bfhi(p.x);
                    float a2 = bflo(p.y), a3 = bfhi(p.y);
                    u4[cl][0] = fmaf(a0, rw[dj + 1], u4[cl][0]);
                    u4[cl][1] = fmaf(a1, rw[dj + 2], u4[cl][1]);
                    u4[cl][2] = fmaf(a2, rw[dj + 3], u4[cl][2]);
                    u4[cl][3] = fmaf(a3, rw[dj + 4], u4[cl][3]);
                }
            }
        }

        float4 s4 = *(const float4*)&sinv[r * 64 + wpx];
        const float* sp = (const float*)&s4;
#pragma unroll
        for (int cl = 0; cl < 2; cl++) {
            int c = c0 + cw + cl;
            float4 v = make_float4(u4[cl][0] * sp[0], u4[cl][1] * sp[1],
                                   u4[cl][2] * sp[2], u4[cl][3] * sp[3]);
            *(float4*)&ub[(size_t)c * PIX + (h0 + r) * 64 + wpx] = v;
        }
        __syncthreads();
    }
}

// ---------------------------------------------------------------------------
extern "C" void kernel_launch(void* const* d_in, const int* in_sizes, int n_in,
                              void* d_out, int out_size, void* d_ws, size_t ws_size,
                              hipStream_t stream) {
    const float* x  = (const float*)d_in[0];
    const float* w1 = (const float*)d_in[1];
    const float* w2 = (const float*)d_in[2];
    const float* w3 = (const float*)d_in[3];
    float* wsf = (float*)d_ws;
    unsigned short* A1hi = (unsigned short*)wsf;
    unsigned short* A1lo = A1hi + 16384;
    unsigned short* A2hi = A1hi + 32768;
    unsigned short* A2lo = A1hi + 49152;

    prep<<<68, 256, 0, stream>>>(w1, w2, w3, A1hi, A1lo, A2hi, A2lo);
    convm<<<512, 256, 0, stream>>>(A1hi, A1lo, x, wsf + Z_OFF);             // z
    simk6<<<896, 256, 0, stream>>>(wsf + Z_OFF, x, wsf + SIM_OFF);          // sim
    softpv8<<<512, 512, 0, stream>>>(wsf + SIM_OFF, x, wsf + U_OFF);        // softmax+PV
    convm<<<512, 256, 0, stream>>>(A2hi, A2lo, wsf + U_OFF, (float*)d_out); // out
}

// Round 17
// 90.441 us; speedup vs baseline: 3.0906x; 1.0443x over previous
//
#include <hip/hip_runtime.h>
#include <math.h>

// Problem constants
constexpr int N = 8, C = 128, H = 64, W = 64;
constexpr int PIX = H * W;            // 4096
constexpr int KK = 49;                // 7x7 window

// ws layout (floats) — first 32768 floats hold 4 bf16 A-matrices (hi/lo x 2)
constexpr size_t Z_OFF   = 65536;                    // z = M^T x
constexpr size_t YSZ     = (size_t)N * C * PIX;      // 4,194,304
constexpr size_t SIM_OFF = Z_OFF + YSZ;              // sim fp32 [g=128][49][256]
constexpr size_t SIMSZ   = (size_t)N * 16 * KK * 256;// 1,605,632
constexpr size_t U_OFF   = SIM_OFF + SIMSZ;          // u = PV(x)

constexpr int SLW = 76;   // fp32 stage row width (simk6)
constexpr int SBW = 76;   // bf16 stage row width in ushorts (softpv9)
constexpr int ALW = 136;  // convm LDS row stride (ushorts)

typedef __attribute__((ext_vector_type(8))) short bf16x8;
typedef __attribute__((ext_vector_type(4))) float f32x4;

__device__ __forceinline__ unsigned bf16rne(float f) {
    unsigned u = __float_as_uint(f);
    u += 0x7FFFu + ((u >> 16) & 1u);
    return u >> 16;
}
__device__ __forceinline__ unsigned packbf(float a, float b) {
    return bf16rne(a) | (bf16rne(b) << 16);
}
__device__ __forceinline__ float bflo(unsigned u) { return __uint_as_float(u << 16); }
__device__ __forceinline__ float bfhi(unsigned u) { return __uint_as_float(u & 0xFFFF0000u); }

// ---------------------------------------------------------------------------
// K0: prep — M = W1^T W2 -> A1 hi/lo bf16; W3 -> A2 hi/lo bf16.  (r15)
// ---------------------------------------------------------------------------
__global__ __launch_bounds__(256) void prep(const float* __restrict__ w1,
                                            const float* __restrict__ w2,
                                            const float* __restrict__ w3,
                                            unsigned short* __restrict__ A1hi,
                                            unsigned short* __restrict__ A1lo,
                                            unsigned short* __restrict__ A2hi,
                                            unsigned short* __restrict__ A2lo) {
    int bid = blockIdx.x, tid = threadIdx.x;
    if (bid < 64) {
        int a = bid * 2 + (tid >> 7);
        int b = tid & 127;
        float s = 0.f;
        for (int c = 0; c < 128; c++)
            s = fmaf(w1[c * 128 + a], w2[c * 128 + b], s);
        unsigned h = bf16rne(s);
        float lo = s - __uint_as_float(h << 16);
        A1hi[b * 128 + a] = (unsigned short)h;
        A1lo[b * 128 + a] = (unsigned short)bf16rne(lo);
    } else {
        int base = (bid - 64) * 4096;
        for (int i = tid; i < 4096; i += 256) {
            int idx = base + i;
            float v = w3[idx];
            unsigned h = bf16rne(v);
            float lo = v - __uint_as_float(h << 16);
            A2hi[idx] = (unsigned short)h;
            A2lo[idx] = (unsigned short)bf16rne(lo);
        }
    }
}

// ---------------------------------------------------------------------------
// K1: split-precision MFMA 1x1-conv (r15, measured-good, unchanged).
// ---------------------------------------------------------------------------
__global__ __launch_bounds__(256) void convm(const unsigned short* __restrict__ Ahi,
                                             const unsigned short* __restrict__ Alo,
                                             const float* __restrict__ Bsrc,
                                             float* __restrict__ Yout) {
    __shared__ __align__(16) unsigned short xh[64 * ALW];
    __shared__ __align__(16) unsigned short xl[64 * ALW];

    int bid = blockIdx.x;
    int pt  = bid & 63;
    int n   = bid >> 6;
    int p0  = pt * 64;

    const float* B = Bsrc + (size_t)n * C * PIX;
    float*       Y = Yout + (size_t)n * C * PIX;

    int tid  = threadIdx.x;
    int wid  = tid >> 6;
    int lane = tid & 63;
    int l15  = lane & 15;
    int lg   = lane >> 4;

    unsigned* xhd = (unsigned*)xh;
    unsigned* xld = (unsigned*)xl;
#pragma unroll
    for (int i = 0; i < 4; i++) {
        int q  = tid + i * 256;
        int cp = q >> 4;
        int f  = q & 15;
        float4 va = *(const float4*)&B[(size_t)(2 * cp) * PIX + p0 + f * 4];
        float4 vb = *(const float4*)&B[(size_t)(2 * cp + 1) * PIX + p0 + f * 4];
        const float* pa = (const float*)&va;
        const float* pb = (const float*)&vb;
#pragma unroll
        for (int j = 0; j < 4; j++) {
            unsigned ha = bf16rne(pa[j]);
            unsigned hb = bf16rne(pb[j]);
            float la = pa[j] - __uint_as_float(ha << 16);
            float lb = pb[j] - __uint_as_float(hb << 16);
            xhd[(f * 4 + j) * 68 + cp] = ha | (hb << 16);
            xld[(f * 4 + j) * 68 + cp] = bf16rne(la) | (bf16rne(lb) << 16);
        }
    }
    __syncthreads();

    f32x4 acc[2][4];
#pragma unroll
    for (int t = 0; t < 2; t++)
#pragma unroll
        for (int p = 0; p < 4; p++) acc[t][p] = (f32x4){0.f, 0.f, 0.f, 0.f};

#pragma unroll
    for (int kc = 0; kc < 4; kc++) {
        int k0 = kc * 32 + lg * 8;
        bf16x8 ah[2], al_[2], bh[4], bl[4];
#pragma unroll
        for (int t = 0; t < 2; t++) {
            int row = wid * 32 + t * 16 + l15;
            ah[t]  = *(const bf16x8*)&Ahi[row * 128 + k0];
            al_[t] = *(const bf16x8*)&Alo[row * 128 + k0];
        }
#pragma unroll
        for (int p = 0; p < 4; p++) {
            bh[p] = *(const bf16x8*)&xh[(p * 16 + l15) * ALW + k0];
            bl[p] = *(const bf16x8*)&xl[(p * 16 + l15) * ALW + k0];
        }
#pragma unroll
        for (int t = 0; t < 2; t++)
#pragma unroll
            for (int p = 0; p < 4; p++) {
                acc[t][p] = __builtin_amdgcn_mfma_f32_16x16x32_bf16(
                    ah[t], bh[p], acc[t][p], 0, 0, 0);
                acc[t][p] = __builtin_amdgcn_mfma_f32_16x16x32_bf16(
                    ah[t], bl[p], acc[t][p], 0, 0, 0);
                acc[t][p] = __builtin_amdgcn_mfma_f32_16x16x32_bf16(
                    al_[t], bh[p], acc[t][p], 0, 0, 0);
            }
    }

#pragma unroll
    for (int t = 0; t < 2; t++) {
#pragma unroll
        for (int p = 0; p < 4; p++) {
#pragma unroll
            for (int reg = 0; reg < 4; reg++) {
                int oc = wid * 32 + t * 16 + lg * 4 + reg;
                int px = p0 + p * 16 + l15;
                Y[(size_t)oc * PIX + px] = acc[t][p][reg];
            }
        }
    }
}

// ---------------------------------------------------------------------------
// K2: simk6 — async-stage split + z prefetch (r16, measured-good, unchanged).
// ---------------------------------------------------------------------------
__global__ __launch_bounds__(256) void simk6(const float* __restrict__ z,
                                             const float* __restrict__ x,
                                             float* __restrict__ sim) {
    __shared__ __align__(16) float st[5376];

    int bid = blockIdx.x;
    int di  = bid >> 7;
    int g   = bid & 127;
    int n   = g >> 4;
    int hq  = g & 15;
    int h0  = hq * 4;

    int tid  = threadIdx.x;
    int wid  = tid >> 6;
    int lane = tid & 63;
    int r = lane >> 4, w4 = lane & 15, wpx = w4 * 4;
    int qw = tid & 15, qc = (tid >> 4) & 15;

    const float* zb = z + (size_t)n * C * PIX;
    const float* xb = x + (size_t)n * C * PIX;
    float* simb = sim + ((size_t)g * KK) * 256;

    for (int idx = tid; idx < 16 * 4 * 8; idx += 256) {
        int col8 = idx & 7;
        int row  = (idx >> 3) & 3;
        int c    = idx >> 5;
        int col  = (col8 < 4) ? col8 : 64 + col8;
        st[(c * 4 + row) * SLW + col] = 0.f;
    }

    float acc[7][4];
#pragma unroll
    for (int dj = 0; dj < 7; dj++)
#pragma unroll
        for (int j = 0; j < 4; j++) acc[dj][j] = 0.f;

    int hh0 = h0 + di - 3;
    float4 xs[2][4], zs[2][4];

#pragma unroll
    for (int i = 0; i < 4; i++) {
        int hh = hh0 + i;
        float4 v = make_float4(0.f, 0.f, 0.f, 0.f);
        if ((unsigned)hh < 64u)
            v = *(const float4*)&xb[(size_t)qc * PIX + hh * 64 + qw * 4];
        xs[0][i] = v;
    }
#pragma unroll
    for (int c = 0; c < 4; c++)
        zs[0][c] = *(const float4*)&zb[(size_t)(wid * 4 + c) * PIX + (h0 + r) * 64 + wpx];

#pragma unroll
    for (int ch = 0; ch < 8; ch++) {
        int cur = ch & 1, nxt = cur ^ 1;
#pragma unroll
        for (int i = 0; i < 4; i++)
            *(float4*)&st[(qc * 4 + i) * SLW + 4 + qw * 4] = xs[cur][i];
        if (ch < 7) {
            int cb = (ch + 1) * 16;
#pragma unroll
            for (int i = 0; i < 4; i++) {
                int hh = hh0 + i;
                float4 v = make_float4(0.f, 0.f, 0.f, 0.f);
                if ((unsigned)hh < 64u)
                    v = *(const float4*)&xb[(size_t)(cb + qc) * PIX + hh * 64 + qw * 4];
                xs[nxt][i] = v;
            }
#pragma unroll
            for (int c = 0; c < 4; c++)
                zs[nxt][c] = *(const float4*)&zb[(size_t)(cb + wid * 4 + c) * PIX
                                                 + (h0 + r) * 64 + wpx];
        }
        __syncthreads();

#pragma unroll
        for (int c = 0; c < 4; c++) {
            int cl = wid * 4 + c;
            const float* rp = &st[(cl * 4 + r) * SLW + wpx];
            float rw[12];
            *(float4*)&rw[0] = *(const float4*)&rp[0];
            *(float4*)&rw[4] = *(const float4*)&rp[4];
            *(float4*)&rw[8] = *(const float4*)&rp[8];
            const float* zp = (const float*)&zs[cur][c];
#pragma unroll
            for (int dj = 0; dj < 7; dj++)
#pragma unroll
                for (int j = 0; j < 4; j++)
                    acc[dj][j] = fmaf(zp[j], rw[j + dj + 1], acc[dj][j]);
        }
        __syncthreads();
    }

    if (wid > 0) {
#pragma unroll
        for (int dj = 0; dj < 7; dj++) {
            float4 v = make_float4(acc[dj][0], acc[dj][1], acc[dj][2], acc[dj][3]);
            *(float4*)&st[((wid - 1) * 7 + dj) * 256 + lane * 4] = v;
        }
    }
    __syncthreads();
    if (wid == 0) {
#pragma unroll
        for (int s = 0; s < 3; s++)
#pragma unroll
            for (int dj = 0; dj < 7; dj++) {
                float4 v = *(const float4*)&st[(s * 7 + dj) * 256 + lane * 4];
                acc[dj][0] += v.x; acc[dj][1] += v.y;
                acc[dj][2] += v.z; acc[dj][3] += v.w;
            }
#pragma unroll
        for (int dj = 0; dj < 7; dj++) {
            int k = di * 7 + dj;
            float4 v = make_float4(acc[dj][0], acc[dj][1], acc[dj][2], acc[dj][3]);
            *(float4*)&simb[(size_t)k * 256 + r * 64 + wpx] = v;
        }
    }
}

// ---------------------------------------------------------------------------
// K3: softpv9 — softpv8 + T14 async-stage split:
//  - chunk-0 x-loads issued at kernel ENTRY (latency hides under softmax)
//  - chunk-1 x-loads issued right after chunk-0 LDS write (hide under PV)
// Same barriers, LDS, math as softpv8.  2-chunk loop unrolled (static idx).
// ---------------------------------------------------------------------------
__global__ __launch_bounds__(512) void softpv9(const float* __restrict__ sim,
                                               const float* __restrict__ x,
                                               float* __restrict__ u) {
    __shared__ __align__(16) unsigned short stb[16 * 10 * SBW];
    __shared__ __align__(16) unsigned short al[KK * 256];
    __shared__ float sinv[256];
    float* mred = (float*)stb;
    float* sred = (float*)stb + 512;

    int bid = blockIdx.x;
    int cqb = bid >> 7;
    int g   = bid & 127;
    int n   = g >> 4;
    int hq  = g & 15;
    int h0  = hq * 4;

    int tid  = threadIdx.x;
    int wid  = tid >> 6;
    int lane = tid & 63;
    int r = lane >> 4, w4 = lane & 15, wpx = w4 * 4;

    const float* simb = sim + (size_t)g * KK * 256;
    const float* xb   = x + (size_t)n * C * PIX;
    float* ub = u + (size_t)n * C * PIX;

    // staging-role indices (fixed per thread, 5 tiles each)
    int sqw[5], sqc[5], sqr[5];
#pragma unroll
    for (int i = 0; i < 5; i++) {
        int q  = tid + i * 512;
        sqw[i] = q & 15; sqc[i] = (q >> 4) & 15; sqr[i] = q >> 8;
    }

    float4 xs[5];
    // ---- T14: issue chunk-0 loads NOW; latency hides under softmax ----
    {
        int c0 = cqb * 32;
#pragma unroll
        for (int i = 0; i < 5; i++) {
            int hh = h0 - 3 + sqr[i];
            float4 v = make_float4(0.f, 0.f, 0.f, 0.f);
            if ((unsigned)hh < 64u)
                v = *(const float4*)&xb[(size_t)(c0 + sqc[i]) * PIX + hh * 64 + sqw[i] * 4];
            xs[i] = v;
        }
    }

    // ---- softmax (deferred normalization) ----
    {
        int ks = tid >> 8;
        int px = tid & 255;
        int k0 = ks ? 25 : 0;
        int nk = ks ? 24 : 25;
        float m = -1e30f;
        for (int i = 0; i < nk; i++)
            m = fmaxf(m, simb[(size_t)(k0 + i) * 256 + px]);
        mred[ks * 256 + px] = m;
        __syncthreads();
        m = fmaxf(mred[px], mred[256 + px]);
        float s = 0.f;
        for (int i = 0; i < nk; i++) {
            float e = __expf(simb[(size_t)(k0 + i) * 256 + px] - m);
            s += e;
            al[(k0 + i) * 256 + px] = (unsigned short)bf16rne(e);
        }
        sred[ks * 256 + px] = s;
        __syncthreads();
        if (ks == 0) sinv[px] = 1.f / (sred[px] + sred[256 + px]);
    }
    __syncthreads();   // sred reads done; stb reusable

    // ---- halo zero ----
    for (int idx = tid; idx < 16 * 10 * 12; idx += 512) {
        int i12  = idx % 12;
        int rowc = idx / 12;
        int col  = (i12 < 4) ? i12 : 64 + i12;
        stb[rowc * SBW + col] = 0;
    }

    // ---- chunk 0: write prefetched regs to LDS; issue chunk-1 loads ----
#pragma unroll
    for (int i = 0; i < 5; i++) {
        uint2 p;
        p.x = packbf(xs[i].x, xs[i].y);
        p.y = packbf(xs[i].z, xs[i].w);
        *(uint2*)&stb[(sqc[i] * 10 + sqr[i]) * SBW + 4 + sqw[i] * 4] = p;
    }
    {
        int c1 = cqb * 32 + 16;
#pragma unroll
        for (int i = 0; i < 5; i++) {
            int hh = h0 - 3 + sqr[i];
            float4 v = make_float4(0.f, 0.f, 0.f, 0.f);
            if ((unsigned)hh < 64u)
                v = *(const float4*)&xb[(size_t)(c1 + sqc[i]) * PIX + hh * 64 + sqw[i] * 4];
            xs[i] = v;
        }
    }
    __syncthreads();   // chunk-0 stage visible

    int cw = wid * 2;
#pragma unroll
    for (int ch2 = 0; ch2 < 2; ch2++) {
        int c0 = cqb * 32 + ch2 * 16;
        float u4[2][4];
#pragma unroll
        for (int cl = 0; cl < 2; cl++)
#pragma unroll
            for (int j = 0; j < 4; j++) u4[cl][j] = 0.f;

        for (int di = 0; di < 7; di++) {
#pragma unroll
            for (int cl = 0; cl < 2; cl++) {
                const unsigned short* rp = &stb[((cw + cl) * 10 + r + di) * SBW + wpx];
                uint2 q0 = *(const uint2*)&rp[0];
                uint2 q1 = *(const uint2*)&rp[4];
                uint2 q2 = *(const uint2*)&rp[8];
                float rw[12];
                rw[0]  = bflo(q0.x); rw[1]  = bfhi(q0.x);
                rw[2]  = bflo(q0.y); rw[3]  = bfhi(q0.y);
                rw[4]  = bflo(q1.x); rw[5]  = bfhi(q1.x);
                rw[6]  = bflo(q1.y); rw[7]  = bfhi(q1.y);
                rw[8]  = bflo(q2.x); rw[9]  = bfhi(q2.x);
                rw[10] = bflo(q2.y); rw[11] = bfhi(q2.y);
#pragma unroll
                for (int dj = 0; dj < 7; dj++) {
                    uint2 p = *(const uint2*)&al[(di * 7 + dj) * 256 + r * 64 + wpx];
                    float a0 = bflo(p.x), a1 = bfhi(p.x);
                    float a2 = bflo(p.y), a3 = bfhi(p.y);
                    u4[cl][0] = fmaf(a0, rw[dj + 1], u4[cl][0]);
                    u4[cl][1] = fmaf(a1, rw[dj + 2], u4[cl][1]);
                    u4[cl][2] = fmaf(a2, rw[dj + 3], u4[cl][2]);
                    u4[cl][3] = fmaf(a3, rw[dj + 4], u4[cl][3]);
                }
            }
        }

        float4 s4 = *(const float4*)&sinv[r * 64 + wpx];
        const float* sp = (const float*)&s4;
#pragma unroll
        for (int cl = 0; cl < 2; cl++) {
            int c = c0 + cw + cl;
            float4 v = make_float4(u4[cl][0] * sp[0], u4[cl][1] * sp[1],
                                   u4[cl][2] * sp[2], u4[cl][3] * sp[3]);
            *(float4*)&ub[(size_t)c * PIX + (h0 + r) * 64 + wpx] = v;
        }

        if (ch2 == 0) {
            __syncthreads();   // chunk-0 compute done; stb writable
#pragma unroll
            for (int i = 0; i < 5; i++) {
                uint2 p;
                p.x = packbf(xs[i].x, xs[i].y);
                p.y = packbf(xs[i].z, xs[i].w);
                *(uint2*)&stb[(sqc[i] * 10 + sqr[i]) * SBW + 4 + sqw[i] * 4] = p;
            }
            __syncthreads();   // chunk-1 stage visible
        }
    }
}

// ---------------------------------------------------------------------------
extern "C" void kernel_launch(void* const* d_in, const int* in_sizes, int n_in,
                              void* d_out, int out_size, void* d_ws, size_t ws_size,
                              hipStream_t stream) {
    const float* x  = (const float*)d_in[0];
    const float* w1 = (const float*)d_in[1];
    const float* w2 = (const float*)d_in[2];
    const float* w3 = (const float*)d_in[3];
    float* wsf = (float*)d_ws;
    unsigned short* A1hi = (unsigned short*)wsf;
    unsigned short* A1lo = A1hi + 16384;
    unsigned short* A2hi = A1hi + 32768;
    unsigned short* A2lo = A1hi + 49152;

    prep<<<68, 256, 0, stream>>>(w1, w2, w3, A1hi, A1lo, A2hi, A2lo);
    convm<<<512, 256, 0, stream>>>(A1hi, A1lo, x, wsf + Z_OFF);             // z
    simk6<<<896, 256, 0, stream>>>(wsf + Z_OFF, x, wsf + SIM_OFF);          // sim
    softpv9<<<512, 512, 0, stream>>>(wsf + SIM_OFF, x, wsf + U_OFF);        // softmax+PV
    convm<<<512, 256, 0, stream>>>(A2hi, A2lo, wsf + U_OFF, (float*)d_out); // out
}